// Round 1
// baseline (4902.061 us; speedup 1.0000x reference)
//
#include <hip/hip_runtime.h>
#include <math.h>

#define N_NODES 20000
#define N_EDGESI 200000
#define E_TOT   220000
#define N_FEAT  2048
#define H1      512
#define H2      30

// ---------------- GEMM1: C[M,N] = A[M,K] @ B[K,N]  (NN, fp32, 64x64 tile) ----
__global__ __launch_bounds__(256) void gemm_nn64(const float* __restrict__ A,
                                                 const float* __restrict__ B,
                                                 float* __restrict__ C,
                                                 int M, int K, int N) {
    __shared__ float As[64 * 17];
    __shared__ float Bs[16 * 64];
    const int bm = blockIdx.y * 64, bn = blockIdx.x * 64;
    const int tid = threadIdx.x;
    const int tx = tid & 15, ty = tid >> 4;
    const int arow = tid >> 2, acol = (tid & 3) * 4;
    const int brow = tid >> 4, bcol = (tid & 15) * 4;
    float c[4][4] = {};
    for (int k0 = 0; k0 < K; k0 += 16) {
        float4 av = make_float4(0.f, 0.f, 0.f, 0.f);
        if (bm + arow < M)
            av = *(const float4*)(A + (size_t)(bm + arow) * K + k0 + acol);
        As[arow * 17 + acol + 0] = av.x;
        As[arow * 17 + acol + 1] = av.y;
        As[arow * 17 + acol + 2] = av.z;
        As[arow * 17 + acol + 3] = av.w;
        float4 bv = *(const float4*)(B + (size_t)(k0 + brow) * N + bn + bcol);
        *(float4*)(Bs + brow * 64 + bcol) = bv;
        __syncthreads();
#pragma unroll
        for (int kk = 0; kk < 16; kk++) {
            float a[4], b[4];
#pragma unroll
            for (int i = 0; i < 4; i++) a[i] = As[(ty * 4 + i) * 17 + kk];
#pragma unroll
            for (int j = 0; j < 4; j++) b[j] = Bs[kk * 64 + tx * 4 + j];
#pragma unroll
            for (int i = 0; i < 4; i++)
#pragma unroll
                for (int j = 0; j < 4; j++) c[i][j] += a[i] * b[j];
        }
        __syncthreads();
    }
#pragma unroll
    for (int i = 0; i < 4; i++) {
        int m = bm + ty * 4 + i;
        if (m < M) {
            float4 v = make_float4(c[i][0], c[i][1], c[i][2], c[i][3]);
            *(float4*)(C + (size_t)m * N + bn + tx * 4) = v;
        }
    }
}

// ---------------- a1s/a1d: per-node dot with att vectors ----------------
__global__ __launch_bounds__(256) void rowdot2(const float* __restrict__ X,
                                               const float* __restrict__ vs,
                                               const float* __restrict__ vd,
                                               float* __restrict__ outs,
                                               float* __restrict__ outd) {
    const int n = blockIdx.x;
    const int t = threadIdx.x;
    float x0 = X[(size_t)n * H1 + t];
    float x1 = X[(size_t)n * H1 + t + 256];
    float s = x0 * vs[t] + x1 * vs[t + 256];
    float d = x0 * vd[t] + x1 * vd[t + 256];
    __shared__ float ss[256], sd[256];
    ss[t] = s; sd[t] = d;
    __syncthreads();
    for (int off = 128; off; off >>= 1) {
        if (t < off) { ss[t] += ss[t + off]; sd[t] += sd[t + off]; }
        __syncthreads();
    }
    if (t == 0) { outs[n] = ss[0]; outd[n] = sd[0]; }
}

// ---------------- edge pass: ex=exp(sigmoid(a1s[s]+a1d[d])); den[d]+=ex ------
__global__ void edge_att(const int* __restrict__ ei,
                         const float* __restrict__ a1s,
                         const float* __restrict__ a1d,
                         float* __restrict__ ebuf,
                         float* __restrict__ den) {
    int e = blockIdx.x * blockDim.x + threadIdx.x;
    if (e >= E_TOT) return;
    int s, d;
    if (e < N_EDGESI) { s = ei[e]; d = ei[N_EDGESI + e]; }
    else { s = e - N_EDGESI; d = s; }
    float x = a1s[s] + a1d[d];
    float sig = 1.f / (1.f + __expf(-x));
    float ex = __expf(sig);
    ebuf[e] = ex;
    unsafeAtomicAdd(&den[d], ex);
}

// ---------------- scatter: Y[d,:] += X[s,:] * coef  (1 wave per edge) --------
__global__ __launch_bounds__(256) void scatter_wave(const int* __restrict__ ei,
                                                    const float* __restrict__ ebuf,
                                                    const float* __restrict__ den,
                                                    const float* __restrict__ X,
                                                    float* __restrict__ Y) {
    int e = blockIdx.x * 4 + (threadIdx.x >> 6);
    int lane = threadIdx.x & 63;
    int s, d;
    if (e < N_EDGESI) { s = ei[e]; d = ei[N_EDGESI + e]; }
    else { s = e - N_EDGESI; d = s; }
    float coef = ebuf[e] / den[d];
    const float4* xs = (const float4*)(X + (size_t)s * H1);
    float* yd = Y + (size_t)d * H1;
    float4 v0 = xs[lane];
    float4 v1 = xs[lane + 64];
    int c0 = lane * 4, c1 = 256 + lane * 4;
    unsafeAtomicAdd(yd + c0 + 0, v0.x * coef);
    unsafeAtomicAdd(yd + c0 + 1, v0.y * coef);
    unsafeAtomicAdd(yd + c0 + 2, v0.z * coef);
    unsafeAtomicAdd(yd + c0 + 3, v0.w * coef);
    unsafeAtomicAdd(yd + c1 + 0, v1.x * coef);
    unsafeAtomicAdd(yd + c1 + 1, v1.y * coef);
    unsafeAtomicAdd(yd + c1 + 2, v1.z * coef);
    unsafeAtomicAdd(yd + c1 + 3, v1.w * coef);
}

// ---------------- elementwise ELU in place ----------------
__global__ void elu_k(float* __restrict__ X, int n) {
    int i = blockIdx.x * blockDim.x + threadIdx.x;
    if (i < n) {
        float x = X[i];
        X[i] = x > 0.f ? x : __expf(x) - 1.f;
    }
}

// ---------------- h2 = normalize_rows(h1 @ W2) : 8 nodes per block ----------
__global__ __launch_bounds__(256) void gemm2_norm(const float* __restrict__ H1b,
                                                  const float* __restrict__ W2,
                                                  float* __restrict__ h2n) {
    __shared__ float hs[8 * 516];
    const int n0 = blockIdx.x * 8;
    const int tid = threadIdx.x;
    for (int idx = tid; idx < 4096; idx += 256) {
        int r = idx >> 9, c = idx & 511;
        hs[r * 516 + c] = H1b[(size_t)(n0 + r) * H1 + c];
    }
    __syncthreads();
    const int sub = tid >> 5, j = tid & 31;
    float acc = 0.f;
    if (j < H2) {
        const float* hr = hs + sub * 516;
        for (int k = 0; k < H1; k++) acc += hr[k] * W2[k * H2 + j];
    }
    float sq = acc * acc;
    for (int m = 16; m; m >>= 1) sq += __shfl_xor(sq, m, 32);
    float inv = 1.f / fmaxf(sqrtf(sq), 1e-12f);
    if (j < H2) h2n[(size_t)(n0 + sub) * H2 + j] = acc * inv;
}

// ---------------- xw3 = h2n @ W2^T : one thread per output element ----------
__global__ void gemm3_k(const float* __restrict__ h2n,
                        const float* __restrict__ W2,
                        float* __restrict__ xw3) {
    int g = blockIdx.x * blockDim.x + threadIdx.x;  // 20000*512
    int n = g >> 9, h = g & 511;
    const float* hr = h2n + (size_t)n * H2;
    const float* wr = W2 + (size_t)h * H2;
    float acc = 0.f;
#pragma unroll
    for (int k = 0; k < H2; k++) acc += hr[k] * wr[k];
    xw3[g] = acc;
}

// ---- GEMM4 (NT) fused MSE: partial += sum((F - A@B^T)^2), no C store -------
__global__ __launch_bounds__(256) void gemm_nt_mse(const float* __restrict__ A,   // h3 [M,512]
                                                   const float* __restrict__ B,   // W1 [2048,512]
                                                   const float* __restrict__ F,   // features [M,2048]
                                                   float* __restrict__ partial) {
    __shared__ float As[64 * 17];
    __shared__ float Bs[64 * 17];
    __shared__ float red[256];
    const int M = N_NODES, K = H1, N = N_FEAT;
    const int bm = blockIdx.y * 64, bn = blockIdx.x * 64;
    const int tid = threadIdx.x;
    const int tx = tid & 15, ty = tid >> 4;
    const int arow = tid >> 2, acol = (tid & 3) * 4;
    float c[4][4] = {};
    for (int k0 = 0; k0 < K; k0 += 16) {
        float4 av = make_float4(0.f, 0.f, 0.f, 0.f);
        if (bm + arow < M)
            av = *(const float4*)(A + (size_t)(bm + arow) * K + k0 + acol);
        As[arow * 17 + acol + 0] = av.x;
        As[arow * 17 + acol + 1] = av.y;
        As[arow * 17 + acol + 2] = av.z;
        As[arow * 17 + acol + 3] = av.w;
        float4 bv = *(const float4*)(B + (size_t)(bn + arow) * K + k0 + acol);
        Bs[arow * 17 + acol + 0] = bv.x;
        Bs[arow * 17 + acol + 1] = bv.y;
        Bs[arow * 17 + acol + 2] = bv.z;
        Bs[arow * 17 + acol + 3] = bv.w;
        __syncthreads();
#pragma unroll
        for (int kk = 0; kk < 16; kk++) {
            float a[4], b[4];
#pragma unroll
            for (int i = 0; i < 4; i++) a[i] = As[(ty * 4 + i) * 17 + kk];
#pragma unroll
            for (int j = 0; j < 4; j++) b[j] = Bs[(tx * 4 + j) * 17 + kk];
#pragma unroll
            for (int i = 0; i < 4; i++)
#pragma unroll
                for (int j = 0; j < 4; j++) c[i][j] += a[i] * b[j];
        }
        __syncthreads();
    }
    float acc = 0.f;
#pragma unroll
    for (int i = 0; i < 4; i++) {
        int m = bm + ty * 4 + i;
        if (m < M) {
            float4 fv = *(const float4*)(F + (size_t)m * N + bn + tx * 4);
            float d0 = fv.x - c[i][0];
            float d1 = fv.y - c[i][1];
            float d2 = fv.z - c[i][2];
            float d3 = fv.w - c[i][3];
            acc += d0 * d0 + d1 * d1 + d2 * d2 + d3 * d3;
        }
    }
    red[tid] = acc;
    __syncthreads();
    for (int off = 128; off; off >>= 1) {
        if (tid < off) red[tid] += red[tid + off];
        __syncthreads();
    }
    if (tid == 0) unsafeAtomicAdd(partial, red[0]);
}

__global__ void finalize_k(const float* __restrict__ partial, float* __restrict__ out) {
    out[0] = partial[0] * (1.f / ((float)N_NODES * (float)N_FEAT));
}

extern "C" void kernel_launch(void* const* d_in, const int* in_sizes, int n_in,
                              void* d_out, int out_size, void* d_ws, size_t ws_size,
                              hipStream_t stream) {
    const float* features = (const float*)d_in[0];
    const int*   ei       = (const int*)d_in[1];
    const float* W1       = (const float*)d_in[2];
    const float* atts     = (const float*)d_in[3];
    const float* attd     = (const float*)d_in[4];
    const float* W2       = (const float*)d_in[5];
    float* out = (float*)d_out;

    float* ws = (float*)d_ws;
    float* bufA    = ws;                       // 10,240,000  (xw1, later xw3)
    float* bufB    = bufA + 10240000;          // 10,240,000  (h1pre/h1, later h3pre/h3)
    float* a1s     = bufB + 10240000;          // 20000
    float* a1d     = a1s + 20000;              // 20000
    float* den     = a1d + 20000;              // 20000
    float* ebuf    = den + 20000;              // 220000
    float* h2n     = ebuf + 220000;            // 600000
    float* partial = h2n + 600000;             // 1

    // zero accumulators
    hipMemsetAsync(bufB, 0, (size_t)10240000 * 4, stream);
    hipMemsetAsync(den, 0, 20000 * 4, stream);
    hipMemsetAsync(partial, 0, 4, stream);

    // 1) xw1 = features @ W1   [20000,512]
    dim3 g1(H1 / 64, (N_NODES + 63) / 64);
    gemm_nn64<<<g1, 256, 0, stream>>>(features, W1, bufA, N_NODES, N_FEAT, H1);

    // 2) attention logits per node
    rowdot2<<<N_NODES, 256, 0, stream>>>(bufA, atts, attd, a1s, a1d);

    // 3) edge attention numerators + denominators
    edge_att<<<(E_TOT + 255) / 256, 256, 0, stream>>>(ei, a1s, a1d, ebuf, den);

    // 4) scatter 1: h1pre[d] += xw1[s]*coef
    scatter_wave<<<E_TOT / 4, 256, 0, stream>>>(ei, ebuf, den, bufA, bufB);

    // 5) h1 = elu(h1pre)
    elu_k<<<(10240000 + 255) / 256, 256, 0, stream>>>(bufB, 10240000);

    // 6) h2n = normalize_rows(h1 @ W2)
    gemm2_norm<<<N_NODES / 8, 256, 0, stream>>>(bufB, W2, h2n);

    // 7) xw3 = h2n @ W2^T  -> bufA (xw1 no longer needed)
    gemm3_k<<<10240000 / 256, 256, 0, stream>>>(h2n, W2, bufA);

    // 8) zero bufB again, scatter 2 with SAME coef
    hipMemsetAsync(bufB, 0, (size_t)10240000 * 4, stream);
    scatter_wave<<<E_TOT / 4, 256, 0, stream>>>(ei, ebuf, den, bufA, bufB);

    // 9) h3 = elu
    elu_k<<<(10240000 + 255) / 256, 256, 0, stream>>>(bufB, 10240000);

    // 10) fused h4 = h3 @ W1^T with MSE reduction
    dim3 g4(N_FEAT / 64, (N_NODES + 63) / 64);
    gemm_nt_mse<<<g4, 256, 0, stream>>>(bufB, W1, features, partial);

    // 11) finalize
    finalize_k<<<1, 1, 0, stream>>>(partial, out);
}

// Round 2
// 2074.650 us; speedup vs baseline: 2.3628x; 2.3628x over previous
//
#include <hip/hip_runtime.h>
#include <math.h>

#define N_NODES 20000
#define N_EDGESI 200000
#define E_TOT   220000
#define N_FEAT  2048
#define H1      512
#define H2      30

// ---------------- GEMM1: C[M,N] = A[M,K] @ B[K,N]  (NN, fp32, 64x64 tile) ----
__global__ __launch_bounds__(256) void gemm_nn64(const float* __restrict__ A,
                                                 const float* __restrict__ B,
                                                 float* __restrict__ C,
                                                 int M, int K, int N) {
    __shared__ float As[64 * 17];
    __shared__ float Bs[16 * 64];
    const int bm = blockIdx.y * 64, bn = blockIdx.x * 64;
    const int tid = threadIdx.x;
    const int tx = tid & 15, ty = tid >> 4;
    const int arow = tid >> 2, acol = (tid & 3) * 4;
    const int brow = tid >> 4, bcol = (tid & 15) * 4;
    float c[4][4] = {};
    for (int k0 = 0; k0 < K; k0 += 16) {
        float4 av = make_float4(0.f, 0.f, 0.f, 0.f);
        if (bm + arow < M)
            av = *(const float4*)(A + (size_t)(bm + arow) * K + k0 + acol);
        As[arow * 17 + acol + 0] = av.x;
        As[arow * 17 + acol + 1] = av.y;
        As[arow * 17 + acol + 2] = av.z;
        As[arow * 17 + acol + 3] = av.w;
        float4 bv = *(const float4*)(B + (size_t)(k0 + brow) * N + bn + bcol);
        *(float4*)(Bs + brow * 64 + bcol) = bv;
        __syncthreads();
#pragma unroll
        for (int kk = 0; kk < 16; kk++) {
            float a[4], b[4];
#pragma unroll
            for (int i = 0; i < 4; i++) a[i] = As[(ty * 4 + i) * 17 + kk];
#pragma unroll
            for (int j = 0; j < 4; j++) b[j] = Bs[kk * 64 + tx * 4 + j];
#pragma unroll
            for (int i = 0; i < 4; i++)
#pragma unroll
                for (int j = 0; j < 4; j++) c[i][j] += a[i] * b[j];
        }
        __syncthreads();
    }
#pragma unroll
    for (int i = 0; i < 4; i++) {
        int m = bm + ty * 4 + i;
        if (m < M) {
            float4 v = make_float4(c[i][0], c[i][1], c[i][2], c[i][3]);
            *(float4*)(C + (size_t)m * N + bn + tx * 4) = v;
        }
    }
}

// ---------------- a1s/a1d: per-node dot with att vectors ----------------
__global__ __launch_bounds__(256) void rowdot2(const float* __restrict__ X,
                                               const float* __restrict__ vs,
                                               const float* __restrict__ vd,
                                               float* __restrict__ outs,
                                               float* __restrict__ outd) {
    const int n = blockIdx.x;
    const int t = threadIdx.x;
    float x0 = X[(size_t)n * H1 + t];
    float x1 = X[(size_t)n * H1 + t + 256];
    float s = x0 * vs[t] + x1 * vs[t + 256];
    float d = x0 * vd[t] + x1 * vd[t + 256];
    __shared__ float ss[256], sd[256];
    ss[t] = s; sd[t] = d;
    __syncthreads();
    for (int off = 128; off; off >>= 1) {
        if (t < off) { ss[t] += ss[t + off]; sd[t] += sd[t + off]; }
        __syncthreads();
    }
    if (t == 0) { outs[n] = ss[0]; outd[n] = sd[0]; }
}

// ---- edge pass: ex=exp(sigmoid(a1s[s]+a1d[d])); den[d]+=ex; deg[d]++ --------
__global__ void edge_att(const int* __restrict__ ei,
                         const float* __restrict__ a1s,
                         const float* __restrict__ a1d,
                         float* __restrict__ ebuf,
                         float* __restrict__ den,
                         int* __restrict__ deg) {
    int e = blockIdx.x * blockDim.x + threadIdx.x;
    if (e >= E_TOT) return;
    int s, d;
    if (e < N_EDGESI) { s = ei[e]; d = ei[N_EDGESI + e]; }
    else { s = e - N_EDGESI; d = s; }
    float x = a1s[s] + a1d[d];
    float sig = 1.f / (1.f + __expf(-x));
    float ex = __expf(sig);
    ebuf[e] = ex;
    unsafeAtomicAdd(&den[d], ex);
    atomicAdd(&deg[d], 1);
}

// ---- exclusive prefix sum over deg[N_NODES] -> off (single 1024-thr block) --
__global__ __launch_bounds__(1024) void scan_k(const int* __restrict__ deg,
                                               int* __restrict__ off) {
    __shared__ int tmp[1024];
    __shared__ int carry_s;
    if (threadIdx.x == 0) carry_s = 0;
    __syncthreads();
    for (int base = 0; base < N_NODES; base += 1024) {
        int i = base + threadIdx.x;
        int v = (i < N_NODES) ? deg[i] : 0;
        tmp[threadIdx.x] = v;
        __syncthreads();
        for (int s = 1; s < 1024; s <<= 1) {
            int t = (threadIdx.x >= s) ? tmp[threadIdx.x - s] : 0;
            __syncthreads();
            tmp[threadIdx.x] += t;
            __syncthreads();
        }
        int c = carry_s;
        int incl = tmp[threadIdx.x];
        __syncthreads();
        if (i < N_NODES) off[i] = c + incl - v;
        if (threadIdx.x == 1023) carry_s = c + incl;
        __syncthreads();
    }
}

// ---- bucket edges into CSR slots; coef = ebuf/den folded in ------------------
__global__ void bucket_k(const int* __restrict__ ei,
                         const float* __restrict__ ebuf,
                         const float* __restrict__ den,
                         int* __restrict__ cursor,
                         int* __restrict__ csr_src,
                         float* __restrict__ csr_coef) {
    int e = blockIdx.x * blockDim.x + threadIdx.x;
    if (e >= E_TOT) return;
    int s, d;
    if (e < N_EDGESI) { s = ei[e]; d = ei[N_EDGESI + e]; }
    else { s = e - N_EDGESI; d = s; }
    int pos = atomicAdd(&cursor[d], 1);
    csr_src[pos] = s;
    csr_coef[pos] = ebuf[e] / den[d];
}

// ---- gather: Y[d,:] = elu( sum_j coef_j * X[src_j,:] ), one wave per node ----
__global__ __launch_bounds__(256) void gather_elu(const int* __restrict__ off,
                                                  const int* __restrict__ csr_src,
                                                  const float* __restrict__ csr_coef,
                                                  const float* __restrict__ X,
                                                  float* __restrict__ Y) {
    int d = blockIdx.x * 4 + (threadIdx.x >> 6);
    int lane = threadIdx.x & 63;
    if (d >= N_NODES) return;
    int beg = off[d];
    int end = (d == N_NODES - 1) ? E_TOT : off[d + 1];
    float4 a0 = make_float4(0.f, 0.f, 0.f, 0.f);
    float4 a1 = make_float4(0.f, 0.f, 0.f, 0.f);
    for (int j = beg; j < end; j++) {
        int s = csr_src[j];
        float c = csr_coef[j];
        const float4* xs = (const float4*)(X + (size_t)s * H1);
        float4 v0 = xs[lane];
        float4 v1 = xs[lane + 64];
        a0.x += v0.x * c; a0.y += v0.y * c; a0.z += v0.z * c; a0.w += v0.w * c;
        a1.x += v1.x * c; a1.y += v1.y * c; a1.z += v1.z * c; a1.w += v1.w * c;
    }
    // ELU
    a0.x = a0.x > 0.f ? a0.x : __expf(a0.x) - 1.f;
    a0.y = a0.y > 0.f ? a0.y : __expf(a0.y) - 1.f;
    a0.z = a0.z > 0.f ? a0.z : __expf(a0.z) - 1.f;
    a0.w = a0.w > 0.f ? a0.w : __expf(a0.w) - 1.f;
    a1.x = a1.x > 0.f ? a1.x : __expf(a1.x) - 1.f;
    a1.y = a1.y > 0.f ? a1.y : __expf(a1.y) - 1.f;
    a1.z = a1.z > 0.f ? a1.z : __expf(a1.z) - 1.f;
    a1.w = a1.w > 0.f ? a1.w : __expf(a1.w) - 1.f;
    float4* yd = (float4*)(Y + (size_t)d * H1);
    yd[lane] = a0;
    yd[lane + 64] = a1;
}

// ---------------- h2 = normalize_rows(h1 @ W2) : 8 nodes per block ----------
__global__ __launch_bounds__(256) void gemm2_norm(const float* __restrict__ H1b,
                                                  const float* __restrict__ W2,
                                                  float* __restrict__ h2n) {
    __shared__ float hs[8 * 516];
    const int n0 = blockIdx.x * 8;
    const int tid = threadIdx.x;
    for (int idx = tid; idx < 4096; idx += 256) {
        int r = idx >> 9, c = idx & 511;
        hs[r * 516 + c] = H1b[(size_t)(n0 + r) * H1 + c];
    }
    __syncthreads();
    const int sub = tid >> 5, j = tid & 31;
    float acc = 0.f;
    if (j < H2) {
        const float* hr = hs + sub * 516;
        for (int k = 0; k < H1; k++) acc += hr[k] * W2[k * H2 + j];
    }
    float sq = acc * acc;
    for (int m = 16; m; m >>= 1) sq += __shfl_xor(sq, m, 32);
    float inv = 1.f / fmaxf(sqrtf(sq), 1e-12f);
    if (j < H2) h2n[(size_t)(n0 + sub) * H2 + j] = acc * inv;
}

// ---------------- xw3 = h2n @ W2^T : one thread per output element ----------
__global__ void gemm3_k(const float* __restrict__ h2n,
                        const float* __restrict__ W2,
                        float* __restrict__ xw3) {
    int g = blockIdx.x * blockDim.x + threadIdx.x;  // 20000*512
    int n = g >> 9, h = g & 511;
    const float* hr = h2n + (size_t)n * H2;
    const float* wr = W2 + (size_t)h * H2;
    float acc = 0.f;
#pragma unroll
    for (int k = 0; k < H2; k++) acc += hr[k] * wr[k];
    xw3[g] = acc;
}

// ---- GEMM4 (NT) fused MSE: partial += sum((F - A@B^T)^2), no C store -------
__global__ __launch_bounds__(256) void gemm_nt_mse(const float* __restrict__ A,   // h3 [M,512]
                                                   const float* __restrict__ B,   // W1 [2048,512]
                                                   const float* __restrict__ F,   // features [M,2048]
                                                   float* __restrict__ partial) {
    __shared__ float As[64 * 17];
    __shared__ float Bs[64 * 17];
    __shared__ float red[256];
    const int M = N_NODES, K = H1, N = N_FEAT;
    const int bm = blockIdx.y * 64, bn = blockIdx.x * 64;
    const int tid = threadIdx.x;
    const int tx = tid & 15, ty = tid >> 4;
    const int arow = tid >> 2, acol = (tid & 3) * 4;
    float c[4][4] = {};
    for (int k0 = 0; k0 < K; k0 += 16) {
        float4 av = make_float4(0.f, 0.f, 0.f, 0.f);
        if (bm + arow < M)
            av = *(const float4*)(A + (size_t)(bm + arow) * K + k0 + acol);
        As[arow * 17 + acol + 0] = av.x;
        As[arow * 17 + acol + 1] = av.y;
        As[arow * 17 + acol + 2] = av.z;
        As[arow * 17 + acol + 3] = av.w;
        float4 bv = *(const float4*)(B + (size_t)(bn + arow) * K + k0 + acol);
        Bs[arow * 17 + acol + 0] = bv.x;
        Bs[arow * 17 + acol + 1] = bv.y;
        Bs[arow * 17 + acol + 2] = bv.z;
        Bs[arow * 17 + acol + 3] = bv.w;
        __syncthreads();
#pragma unroll
        for (int kk = 0; kk < 16; kk++) {
            float a[4], b[4];
#pragma unroll
            for (int i = 0; i < 4; i++) a[i] = As[(ty * 4 + i) * 17 + kk];
#pragma unroll
            for (int j = 0; j < 4; j++) b[j] = Bs[(tx * 4 + j) * 17 + kk];
#pragma unroll
            for (int i = 0; i < 4; i++)
#pragma unroll
                for (int j = 0; j < 4; j++) c[i][j] += a[i] * b[j];
        }
        __syncthreads();
    }
    float acc = 0.f;
#pragma unroll
    for (int i = 0; i < 4; i++) {
        int m = bm + ty * 4 + i;
        if (m < M) {
            float4 fv = *(const float4*)(F + (size_t)m * N + bn + tx * 4);
            float d0 = fv.x - c[i][0];
            float d1 = fv.y - c[i][1];
            float d2 = fv.z - c[i][2];
            float d3 = fv.w - c[i][3];
            acc += d0 * d0 + d1 * d1 + d2 * d2 + d3 * d3;
        }
    }
    red[tid] = acc;
    __syncthreads();
    for (int off = 128; off; off >>= 1) {
        if (tid < off) red[tid] += red[tid + off];
        __syncthreads();
    }
    if (tid == 0) unsafeAtomicAdd(partial, red[0]);
}

__global__ void finalize_k(const float* __restrict__ partial, float* __restrict__ out) {
    out[0] = partial[0] * (1.f / ((float)N_NODES * (float)N_FEAT));
}

extern "C" void kernel_launch(void* const* d_in, const int* in_sizes, int n_in,
                              void* d_out, int out_size, void* d_ws, size_t ws_size,
                              hipStream_t stream) {
    const float* features = (const float*)d_in[0];
    const int*   ei       = (const int*)d_in[1];
    const float* W1       = (const float*)d_in[2];
    const float* atts     = (const float*)d_in[3];
    const float* attd     = (const float*)d_in[4];
    const float* W2       = (const float*)d_in[5];
    float* out = (float*)d_out;

    float* ws = (float*)d_ws;
    float* bufA    = ws;                       // 10,240,000  (xw1, later xw3)
    float* bufB    = bufA + 10240000;          // 10,240,000  (h1, later h3)
    float* a1s     = bufB + 10240000;          // 20000
    float* a1d     = a1s + 20000;              // 20000
    float* den     = a1d + 20000;              // 20000
    float* ebuf    = den + 20000;              // 220000
    float* h2n     = ebuf + 220000;            // 600000
    float* partial = h2n + 600000;             // 1
    int*   deg     = (int*)(partial + 1);      // 20000
    int*   off     = deg + 20000;              // 20000
    int*   cursor  = off + 20000;              // 20000
    int*   csr_src = cursor + 20000;           // 220000
    float* csr_coef= (float*)(csr_src + 220000); // 220000

    // zero accumulators
    hipMemsetAsync(den, 0, 20000 * 4, stream);
    hipMemsetAsync(deg, 0, 20000 * 4, stream);
    hipMemsetAsync(partial, 0, 4, stream);

    // 1) xw1 = features @ W1   [20000,512]
    dim3 g1(H1 / 64, (N_NODES + 63) / 64);
    gemm_nn64<<<g1, 256, 0, stream>>>(features, W1, bufA, N_NODES, N_FEAT, H1);

    // 2) attention logits per node
    rowdot2<<<N_NODES, 256, 0, stream>>>(bufA, atts, attd, a1s, a1d);

    // 3) edge attention numerators + denominators + degree counts
    edge_att<<<(E_TOT + 255) / 256, 256, 0, stream>>>(ei, a1s, a1d, ebuf, den, deg);

    // 4) CSR build: scan degrees, bucket edges
    scan_k<<<1, 1024, 0, stream>>>(deg, off);
    hipMemcpyAsync(cursor, off, 20000 * 4, hipMemcpyDeviceToDevice, stream);
    bucket_k<<<(E_TOT + 255) / 256, 256, 0, stream>>>(ei, ebuf, den, cursor, csr_src, csr_coef);

    // 5) h1 = elu(gather(xw1))
    gather_elu<<<N_NODES / 4, 256, 0, stream>>>(off, csr_src, csr_coef, bufA, bufB);

    // 6) h2n = normalize_rows(h1 @ W2)
    gemm2_norm<<<N_NODES / 8, 256, 0, stream>>>(bufB, W2, h2n);

    // 7) xw3 = h2n @ W2^T  -> bufA (xw1 no longer needed)
    gemm3_k<<<10240000 / 256, 256, 0, stream>>>(h2n, W2, bufA);

    // 8) h3 = elu(gather(xw3))
    gather_elu<<<N_NODES / 4, 256, 0, stream>>>(off, csr_src, csr_coef, bufA, bufB);

    // 9) fused h4 = h3 @ W1^T with MSE reduction
    dim3 g4(N_FEAT / 64, (N_NODES + 63) / 64);
    gemm_nt_mse<<<g4, 256, 0, stream>>>(bufB, W1, features, partial);

    // 10) finalize
    finalize_k<<<1, 1, 0, stream>>>(partial, out);
}

// Round 3
// 811.621 us; speedup vs baseline: 6.0398x; 2.5562x over previous
//
#include <hip/hip_runtime.h>
#include <math.h>

#define N_NODES 20000
#define N_EDGESI 200000
#define E_TOT   220000
#define N_FEAT  2048
#define H1      512
#define H2      30

typedef __bf16 bf16x8 __attribute__((ext_vector_type(8)));
typedef float  floatx4 __attribute__((ext_vector_type(4)));

__device__ __forceinline__ unsigned short f2bf(float f) {   // RNE
    unsigned int u = __float_as_uint(f);
    unsigned int r = (u + 0x7FFF + ((u >> 16) & 1)) >> 16;
    return (unsigned short)r;
}
__device__ __forceinline__ float bf2f(unsigned short u) {
    return __uint_as_float(((unsigned int)u) << 16);
}
// fast truncation-pack of two floats into packed bf16x2 (for hot staging path)
__device__ __forceinline__ unsigned int packtrunc(float a, float b) {
    return (__float_as_uint(a) >> 16) | (__float_as_uint(b) & 0xFFFF0000u);
}
__device__ __forceinline__ unsigned int packrne(float a, float b) {
    return (unsigned int)f2bf(a) | ((unsigned int)f2bf(b) << 16);
}

// ---- W1 conversion: w1bf[k][n] (straight) + w1tbf[n][k] (transposed) -------
__global__ __launch_bounds__(256) void cvtW1(const float* __restrict__ W1,
                                             unsigned short* __restrict__ w1bf,
                                             unsigned short* __restrict__ w1tbf) {
    __shared__ float tile[32][33];
    const int bk = blockIdx.y * 32, bn = blockIdx.x * 32;
    const int tc = threadIdx.x & 31, tr = threadIdx.x >> 5;  // 8 rows/pass
    for (int r = tr; r < 32; r += 8) {
        float v = W1[(size_t)(bk + r) * H1 + bn + tc];
        w1bf[(size_t)(bk + r) * H1 + bn + tc] = f2bf(v);
        tile[r][tc] = v;
    }
    __syncthreads();
    for (int r = tr; r < 32; r += 8) {
        w1tbf[(size_t)(bn + r) * N_FEAT + bk + tc] = f2bf(tile[tc][r]);
    }
}

// ---- GEMM1 (MFMA): xw1bf[m][n] = features[m][:] . W1t[n][:]  (fp32 A cvt) ---
__global__ __launch_bounds__(256) void gemm1_mfma(const float* __restrict__ A,          // [20000,2048] fp32
                                                  const unsigned short* __restrict__ Bt, // [512,2048] bf16
                                                  unsigned short* __restrict__ C) {      // [20000,512] bf16
    __shared__ unsigned short As[128 * 40];
    __shared__ unsigned short Bs[128 * 40];
    const int bm = blockIdx.y * 128, bn = blockIdx.x * 128;
    const int t = threadIdx.x;
    const int lane = t & 63, w = t >> 6;
    const int wm = w >> 1, wn = w & 1;
    const int ln = lane & 15, qd = lane >> 4;
    const int r0 = t >> 2, cs = (t & 3) * 8;

    floatx4 acc[4][4];
#pragma unroll
    for (int i = 0; i < 4; i++)
#pragma unroll
        for (int j = 0; j < 4; j++) acc[i][j] = (floatx4){0.f, 0.f, 0.f, 0.f};

    for (int k0 = 0; k0 < N_FEAT; k0 += 32) {
        // stage A (fp32 -> bf16 trunc-pack): 2 segments of 8 elems per thread
#pragma unroll
        for (int part = 0; part < 2; part++) {
            int r = r0 + part * 64;
            int gr = bm + r; if (gr > N_NODES - 1) gr = N_NODES - 1;
            const float* ap = A + (size_t)gr * N_FEAT + k0 + cs;
            float4 u0 = *(const float4*)ap;
            float4 u1 = *(const float4*)(ap + 4);
            uint4 pk;
            pk.x = packtrunc(u0.x, u0.y);
            pk.y = packtrunc(u0.z, u0.w);
            pk.z = packtrunc(u1.x, u1.y);
            pk.w = packtrunc(u1.z, u1.w);
            *(uint4*)&As[r * 40 + cs] = pk;
        }
        // stage B (already bf16)
#pragma unroll
        for (int part = 0; part < 2; part++) {
            int r = r0 + part * 64;
            const unsigned short* bp = Bt + (size_t)(bn + r) * N_FEAT + k0 + cs;
            *(uint4*)&Bs[r * 40 + cs] = *(const uint4*)bp;
        }
        __syncthreads();
        bf16x8 af[4], bfr[4];
        const unsigned short* Ab = As + (size_t)(wm * 64 + ln) * 40 + qd * 8;
        const unsigned short* Bb = Bs + (size_t)(wn * 64 + ln) * 40 + qd * 8;
#pragma unroll
        for (int i = 0; i < 4; i++) af[i]  = *(const bf16x8*)(const void*)(Ab + i * 16 * 40);
#pragma unroll
        for (int j = 0; j < 4; j++) bfr[j] = *(const bf16x8*)(const void*)(Bb + j * 16 * 40);
#pragma unroll
        for (int i = 0; i < 4; i++)
#pragma unroll
            for (int j = 0; j < 4; j++)
                acc[i][j] = __builtin_amdgcn_mfma_f32_16x16x32_bf16(af[i], bfr[j], acc[i][j], 0, 0, 0);
        __syncthreads();
    }
#pragma unroll
    for (int i = 0; i < 4; i++)
#pragma unroll
        for (int j = 0; j < 4; j++)
#pragma unroll
            for (int p = 0; p < 4; p++) {
                int m = bm + wm * 64 + i * 16 + qd * 4 + p;
                if (m < N_NODES) {
                    int n = bn + wn * 64 + j * 16 + ln;
                    C[(size_t)m * H1 + n] = f2bf(acc[i][j][p]);
                }
            }
}

// ---- GEMM4 (MFMA, fused MSE): sum += (F - h3@W1^T)^2 ------------------------
__global__ __launch_bounds__(256) void gemm4_mse(const unsigned short* __restrict__ A,  // h3bf [20000,512]
                                                 const unsigned short* __restrict__ B,  // w1bf [2048,512]
                                                 const float* __restrict__ F,           // [20000,2048] fp32
                                                 float* __restrict__ partial) {
    __shared__ unsigned short As[128 * 40];
    __shared__ unsigned short Bs[128 * 40];
    __shared__ float red[256];
    const int bm = blockIdx.y * 128, bn = blockIdx.x * 128;
    const int t = threadIdx.x;
    const int lane = t & 63, w = t >> 6;
    const int wm = w >> 1, wn = w & 1;
    const int ln = lane & 15, qd = lane >> 4;
    const int r0 = t >> 2, cs = (t & 3) * 8;

    floatx4 acc[4][4];
#pragma unroll
    for (int i = 0; i < 4; i++)
#pragma unroll
        for (int j = 0; j < 4; j++) acc[i][j] = (floatx4){0.f, 0.f, 0.f, 0.f};

    for (int k0 = 0; k0 < H1; k0 += 32) {
#pragma unroll
        for (int part = 0; part < 2; part++) {
            int r = r0 + part * 64;
            int gr = bm + r; if (gr > N_NODES - 1) gr = N_NODES - 1;
            *(uint4*)&As[r * 40 + cs] = *(const uint4*)(A + (size_t)gr * H1 + k0 + cs);
            *(uint4*)&Bs[r * 40 + cs] = *(const uint4*)(B + (size_t)(bn + r) * H1 + k0 + cs);
        }
        __syncthreads();
        bf16x8 af[4], bfr[4];
        const unsigned short* Ab = As + (size_t)(wm * 64 + ln) * 40 + qd * 8;
        const unsigned short* Bb = Bs + (size_t)(wn * 64 + ln) * 40 + qd * 8;
#pragma unroll
        for (int i = 0; i < 4; i++) af[i]  = *(const bf16x8*)(const void*)(Ab + i * 16 * 40);
#pragma unroll
        for (int j = 0; j < 4; j++) bfr[j] = *(const bf16x8*)(const void*)(Bb + j * 16 * 40);
#pragma unroll
        for (int i = 0; i < 4; i++)
#pragma unroll
            for (int j = 0; j < 4; j++)
                acc[i][j] = __builtin_amdgcn_mfma_f32_16x16x32_bf16(af[i], bfr[j], acc[i][j], 0, 0, 0);
        __syncthreads();
    }
    float sum = 0.f;
#pragma unroll
    for (int i = 0; i < 4; i++)
#pragma unroll
        for (int j = 0; j < 4; j++)
#pragma unroll
            for (int p = 0; p < 4; p++) {
                int m = bm + wm * 64 + i * 16 + qd * 4 + p;
                if (m < N_NODES) {
                    int n = bn + wn * 64 + j * 16 + ln;
                    float fv = F[(size_t)m * N_FEAT + n];
                    float d = fv - acc[i][j][p];
                    sum += d * d;
                }
            }
    red[t] = sum;
    __syncthreads();
    for (int off = 128; off; off >>= 1) {
        if (t < off) red[t] += red[t + off];
        __syncthreads();
    }
    if (t == 0) unsafeAtomicAdd(partial, red[0]);
}

// ---- a1s/a1d from bf16 xw1 --------------------------------------------------
__global__ __launch_bounds__(256) void rowdot2_bf(const unsigned short* __restrict__ X,
                                                  const float* __restrict__ vs,
                                                  const float* __restrict__ vd,
                                                  float* __restrict__ outs,
                                                  float* __restrict__ outd) {
    const int n = blockIdx.x;
    const int t = threadIdx.x;
    float x0 = bf2f(X[(size_t)n * H1 + t]);
    float x1 = bf2f(X[(size_t)n * H1 + t + 256]);
    float s = x0 * vs[t] + x1 * vs[t + 256];
    float d = x0 * vd[t] + x1 * vd[t + 256];
    __shared__ float ss[256], sd[256];
    ss[t] = s; sd[t] = d;
    __syncthreads();
    for (int off = 128; off; off >>= 1) {
        if (t < off) { ss[t] += ss[t + off]; sd[t] += sd[t + off]; }
        __syncthreads();
    }
    if (t == 0) { outs[n] = ss[0]; outd[n] = sd[0]; }
}

// ---- edge pass --------------------------------------------------------------
__global__ void edge_att(const int* __restrict__ ei,
                         const float* __restrict__ a1s,
                         const float* __restrict__ a1d,
                         float* __restrict__ ebuf,
                         float* __restrict__ den,
                         int* __restrict__ deg) {
    int e = blockIdx.x * blockDim.x + threadIdx.x;
    if (e >= E_TOT) return;
    int s, d;
    if (e < N_EDGESI) { s = ei[e]; d = ei[N_EDGESI + e]; }
    else { s = e - N_EDGESI; d = s; }
    float x = a1s[s] + a1d[d];
    float sig = 1.f / (1.f + __expf(-x));
    float ex = __expf(sig);
    ebuf[e] = ex;
    unsafeAtomicAdd(&den[d], ex);
    atomicAdd(&deg[d], 1);
}

// ---- exclusive prefix sum over deg -> off ----------------------------------
__global__ __launch_bounds__(1024) void scan_k(const int* __restrict__ deg,
                                               int* __restrict__ off) {
    __shared__ int tmp[1024];
    __shared__ int carry_s;
    if (threadIdx.x == 0) carry_s = 0;
    __syncthreads();
    for (int base = 0; base < N_NODES; base += 1024) {
        int i = base + threadIdx.x;
        int v = (i < N_NODES) ? deg[i] : 0;
        tmp[threadIdx.x] = v;
        __syncthreads();
        for (int s = 1; s < 1024; s <<= 1) {
            int tt = (threadIdx.x >= s) ? tmp[threadIdx.x - s] : 0;
            __syncthreads();
            tmp[threadIdx.x] += tt;
            __syncthreads();
        }
        int c = carry_s;
        int incl = tmp[threadIdx.x];
        __syncthreads();
        if (i < N_NODES) off[i] = c + incl - v;
        if (threadIdx.x == 1023) carry_s = c + incl;
        __syncthreads();
    }
}

// ---- bucket edges into CSR slots -------------------------------------------
__global__ void bucket_k(const int* __restrict__ ei,
                         const float* __restrict__ ebuf,
                         const float* __restrict__ den,
                         int* __restrict__ cursor,
                         int* __restrict__ csr_src,
                         float* __restrict__ csr_coef) {
    int e = blockIdx.x * blockDim.x + threadIdx.x;
    if (e >= E_TOT) return;
    int s, d;
    if (e < N_EDGESI) { s = ei[e]; d = ei[N_EDGESI + e]; }
    else { s = e - N_EDGESI; d = s; }
    int pos = atomicAdd(&cursor[d], 1);
    csr_src[pos] = s;
    csr_coef[pos] = ebuf[e] / den[d];
}

// ---- gather (bf16 in, bf16 out): Y[d] = elu(sum coef * X[src]) --------------
__global__ __launch_bounds__(256) void gather_elu_bf(const int* __restrict__ off,
                                                     const int* __restrict__ csr_src,
                                                     const float* __restrict__ csr_coef,
                                                     const unsigned short* __restrict__ X,
                                                     unsigned short* __restrict__ Y) {
    int d = blockIdx.x * 4 + (threadIdx.x >> 6);
    int lane = threadIdx.x & 63;
    if (d >= N_NODES) return;
    int beg = off[d];
    int end = (d == N_NODES - 1) ? E_TOT : off[d + 1];
    float a[8] = {0.f, 0.f, 0.f, 0.f, 0.f, 0.f, 0.f, 0.f};
    for (int j = beg; j < end; j++) {
        int s = csr_src[j];
        float c = csr_coef[j];
        uint4 raw = *(const uint4*)(X + (size_t)s * H1 + lane * 8);
        a[0] += __uint_as_float(raw.x << 16) * c;
        a[1] += __uint_as_float(raw.x & 0xFFFF0000u) * c;
        a[2] += __uint_as_float(raw.y << 16) * c;
        a[3] += __uint_as_float(raw.y & 0xFFFF0000u) * c;
        a[4] += __uint_as_float(raw.z << 16) * c;
        a[5] += __uint_as_float(raw.z & 0xFFFF0000u) * c;
        a[6] += __uint_as_float(raw.w << 16) * c;
        a[7] += __uint_as_float(raw.w & 0xFFFF0000u) * c;
    }
#pragma unroll
    for (int e = 0; e < 8; e++) a[e] = a[e] > 0.f ? a[e] : __expf(a[e]) - 1.f;
    uint4 o;
    o.x = packrne(a[0], a[1]);
    o.y = packrne(a[2], a[3]);
    o.z = packrne(a[4], a[5]);
    o.w = packrne(a[6], a[7]);
    *(uint4*)(Y + (size_t)d * H1 + lane * 8) = o;
}

// ---- h2 = normalize_rows(h1 @ W2), h1 in bf16 -------------------------------
__global__ __launch_bounds__(256) void gemm2_norm_bf(const unsigned short* __restrict__ H1b,
                                                     const float* __restrict__ W2,
                                                     float* __restrict__ h2n) {
    __shared__ float hs[8 * 516];
    const int n0 = blockIdx.x * 8;
    const int tid = threadIdx.x;
    for (int idx = tid; idx < 4096; idx += 256) {
        int r = idx >> 9, c = idx & 511;
        hs[r * 516 + c] = bf2f(H1b[(size_t)(n0 + r) * H1 + c]);
    }
    __syncthreads();
    const int sub = tid >> 5, j = tid & 31;
    float acc = 0.f;
    if (j < H2) {
        const float* hr = hs + sub * 516;
        for (int k = 0; k < H1; k++) acc += hr[k] * W2[k * H2 + j];
    }
    float sq = acc * acc;
    for (int m = 16; m; m >>= 1) sq += __shfl_xor(sq, m, 32);
    float inv = 1.f / fmaxf(sqrtf(sq), 1e-12f);
    if (j < H2) h2n[(size_t)(n0 + sub) * H2 + j] = acc * inv;
}

// ---- xw3 = h2n @ W2^T -> bf16 ----------------------------------------------
__global__ void gemm3_k(const float* __restrict__ h2n,
                        const float* __restrict__ W2,
                        unsigned short* __restrict__ xw3) {
    int g = blockIdx.x * blockDim.x + threadIdx.x;  // 20000*512
    int n = g >> 9, h = g & 511;
    const float* hr = h2n + (size_t)n * H2;
    const float* wr = W2 + (size_t)h * H2;
    float acc = 0.f;
#pragma unroll
    for (int k = 0; k < H2; k++) acc += hr[k] * wr[k];
    xw3[g] = f2bf(acc);
}

__global__ void finalize_k(const float* __restrict__ partial, float* __restrict__ out) {
    out[0] = partial[0] * (1.f / ((float)N_NODES * (float)N_FEAT));
}

extern "C" void kernel_launch(void* const* d_in, const int* in_sizes, int n_in,
                              void* d_out, int out_size, void* d_ws, size_t ws_size,
                              hipStream_t stream) {
    const float* features = (const float*)d_in[0];
    const int*   ei       = (const int*)d_in[1];
    const float* W1       = (const float*)d_in[2];
    const float* atts     = (const float*)d_in[3];
    const float* attd     = (const float*)d_in[4];
    const float* W2       = (const float*)d_in[5];
    float* out = (float*)d_out;

    char* ws = (char*)d_ws;
    unsigned short* xw1bf = (unsigned short*)(ws);              // 20,480,000 B (also xw3bf)
    unsigned short* h3bf  = (unsigned short*)(ws + 20480000);   // 20,480,000 B
    unsigned short* h1bf  = (unsigned short*)(ws + 40960000);   // 20,480,000 B
    unsigned short* w1bf  = (unsigned short*)(ws + 61440000);   //  2,097,152 B
    unsigned short* w1tbf = (unsigned short*)(ws + 63537152);   //  2,097,152 B
    float* h2n      = (float*)(ws + 65634304);                  //  2,400,000 B
    float* a1s      = (float*)(ws + 68034304);
    float* a1d      = (float*)(ws + 68114304);
    float* den      = (float*)(ws + 68194304);
    float* ebuf     = (float*)(ws + 68274304);                  //    880,000 B
    int*   deg      = (int*)  (ws + 69154304);
    int*   off      = (int*)  (ws + 69234304);
    int*   cursor   = (int*)  (ws + 69314304);
    int*   csr_src  = (int*)  (ws + 69394304);                  //    880,000 B
    float* csr_coef = (float*)(ws + 70274304);                  //    880,000 B
    float* partial  = (float*)(ws + 71154304);

    hipMemsetAsync(den, 0, 20000 * 4, stream);
    hipMemsetAsync(deg, 0, 20000 * 4, stream);
    hipMemsetAsync(partial, 0, 4, stream);

    // 0) W1 -> bf16 (straight + transposed)
    cvtW1<<<dim3(16, 64), 256, 0, stream>>>(W1, w1bf, w1tbf);

    // 1) xw1 = features @ W1 (MFMA, bf16 out)
    gemm1_mfma<<<dim3(4, 157), 256, 0, stream>>>(features, w1tbf, xw1bf);

    // 2) attention logits per node
    rowdot2_bf<<<N_NODES, 256, 0, stream>>>(xw1bf, atts, attd, a1s, a1d);

    // 3) edge attention numerators + denominators + degree counts
    edge_att<<<(E_TOT + 255) / 256, 256, 0, stream>>>(ei, a1s, a1d, ebuf, den, deg);

    // 4) CSR build
    scan_k<<<1, 1024, 0, stream>>>(deg, off);
    hipMemcpyAsync(cursor, off, 20000 * 4, hipMemcpyDeviceToDevice, stream);
    bucket_k<<<(E_TOT + 255) / 256, 256, 0, stream>>>(ei, ebuf, den, cursor, csr_src, csr_coef);

    // 5) h1 = elu(gather(xw1))
    gather_elu_bf<<<N_NODES / 4, 256, 0, stream>>>(off, csr_src, csr_coef, xw1bf, h1bf);

    // 6) h2n = normalize_rows(h1 @ W2)
    gemm2_norm_bf<<<N_NODES / 8, 256, 0, stream>>>(h1bf, W2, h2n);

    // 7) xw3 = h2n @ W2^T (bf16 out, reuses xw1bf buffer)
    gemm3_k<<<10240000 / 256, 256, 0, stream>>>(h2n, W2, xw1bf);

    // 8) h3 = elu(gather(xw3))
    gather_elu_bf<<<N_NODES / 4, 256, 0, stream>>>(off, csr_src, csr_coef, xw1bf, h3bf);

    // 9) fused h4 = h3 @ W1^T with MSE reduction (MFMA)
    gemm4_mse<<<dim3(16, 157), 256, 0, stream>>>(h3bf, w1bf, features, partial);

    // 10) finalize
    finalize_k<<<1, 1, 0, stream>>>(partial, out);
}

// Round 4
// 766.986 us; speedup vs baseline: 6.3913x; 1.0582x over previous
//
#include <hip/hip_runtime.h>
#include <math.h>

#define N_NODES 20000
#define N_EDGESI 200000
#define E_TOT   220000
#define N_FEAT  2048
#define H1      512
#define H2      30

typedef __bf16 bf16x8 __attribute__((ext_vector_type(8)));
typedef float  floatx4 __attribute__((ext_vector_type(4)));

__device__ __forceinline__ unsigned short f2bf(float f) {   // RNE
    unsigned int u = __float_as_uint(f);
    unsigned int r = (u + 0x7FFF + ((u >> 16) & 1)) >> 16;
    return (unsigned short)r;
}
__device__ __forceinline__ float bf2f(unsigned short u) {
    return __uint_as_float(((unsigned int)u) << 16);
}
__device__ __forceinline__ unsigned int packtrunc(float a, float b) {
    return (__float_as_uint(a) >> 16) | (__float_as_uint(b) & 0xFFFF0000u);
}
__device__ __forceinline__ unsigned int packrne(float a, float b) {
    return (unsigned int)f2bf(a) | ((unsigned int)f2bf(b) << 16);
}

// ---- W1 conversion: w1bf[k][n] (straight) + w1tbf[n][k] (transposed) -------
__global__ __launch_bounds__(256) void cvtW1(const float* __restrict__ W1,
                                             unsigned short* __restrict__ w1bf,
                                             unsigned short* __restrict__ w1tbf) {
    __shared__ float tile[32][33];
    const int bk = blockIdx.y * 32, bn = blockIdx.x * 32;
    const int tc = threadIdx.x & 31, tr = threadIdx.x >> 5;  // 8 rows/pass
    for (int r = tr; r < 32; r += 8) {
        float v = W1[(size_t)(bk + r) * H1 + bn + tc];
        w1bf[(size_t)(bk + r) * H1 + bn + tc] = f2bf(v);
        tile[r][tc] = v;
    }
    __syncthreads();
    for (int r = tr; r < 32; r += 8) {
        w1tbf[(size_t)(bn + r) * N_FEAT + bk + tc] = f2bf(tile[tc][r]);
    }
}

// ---- GEMM1 (MFMA): xw1 = features @ W1, fused a1s/a1d epilogue --------------
// grid: 640 blocks, XCD-swizzled so the 4 N-tiles of a stripe share an XCD/L2.
__global__ __launch_bounds__(256) void gemm1_mfma(const float* __restrict__ A,          // [20000,2048] fp32
                                                  const unsigned short* __restrict__ Bt, // [512,2048] bf16
                                                  unsigned short* __restrict__ C,        // [20000,512] bf16
                                                  const float* __restrict__ atts,
                                                  const float* __restrict__ attd,
                                                  float* __restrict__ a1s,
                                                  float* __restrict__ a1d) {
    __shared__ unsigned short As[128 * 40];
    __shared__ unsigned short Bs[128 * 40];
    const int blk = blockIdx.x;
    const int xcd = blk & 7, rr = blk >> 3;
    const int ntile = rr & 3, group = rr >> 2;
    const int stripe = group * 8 + xcd;
    if (stripe >= 157) return;
    const int bm = stripe * 128, bn = ntile * 128;
    const int t = threadIdx.x;
    const int lane = t & 63, w = t >> 6;
    const int wm = w >> 1, wn = w & 1;
    const int ln = lane & 15, qd = lane >> 4;
    const int r0 = t >> 2, cs = (t & 3) * 8;

    floatx4 acc[4][4];
#pragma unroll
    for (int i = 0; i < 4; i++)
#pragma unroll
        for (int j = 0; j < 4; j++) acc[i][j] = (floatx4){0.f, 0.f, 0.f, 0.f};

    for (int k0 = 0; k0 < N_FEAT; k0 += 32) {
#pragma unroll
        for (int part = 0; part < 2; part++) {
            int r = r0 + part * 64;
            int gr = bm + r; if (gr > N_NODES - 1) gr = N_NODES - 1;
            const float* ap = A + (size_t)gr * N_FEAT + k0 + cs;
            float4 u0 = *(const float4*)ap;
            float4 u1 = *(const float4*)(ap + 4);
            uint4 pk;
            pk.x = packtrunc(u0.x, u0.y);
            pk.y = packtrunc(u0.z, u0.w);
            pk.z = packtrunc(u1.x, u1.y);
            pk.w = packtrunc(u1.z, u1.w);
            *(uint4*)&As[r * 40 + cs] = pk;
            const unsigned short* bp = Bt + (size_t)(bn + r) * N_FEAT + k0 + cs;
            *(uint4*)&Bs[r * 40 + cs] = *(const uint4*)bp;
        }
        __syncthreads();
        bf16x8 af[4], bfr[4];
        const unsigned short* Ab = As + (size_t)(wm * 64 + ln) * 40 + qd * 8;
        const unsigned short* Bb = Bs + (size_t)(wn * 64 + ln) * 40 + qd * 8;
#pragma unroll
        for (int i = 0; i < 4; i++) af[i]  = *(const bf16x8*)(const void*)(Ab + i * 16 * 40);
#pragma unroll
        for (int j = 0; j < 4; j++) bfr[j] = *(const bf16x8*)(const void*)(Bb + j * 16 * 40);
#pragma unroll
        for (int i = 0; i < 4; i++)
#pragma unroll
            for (int j = 0; j < 4; j++)
                acc[i][j] = __builtin_amdgcn_mfma_f32_16x16x32_bf16(af[i], bfr[j], acc[i][j], 0, 0, 0);
        __syncthreads();
    }
    // C write
#pragma unroll
    for (int i = 0; i < 4; i++)
#pragma unroll
        for (int j = 0; j < 4; j++)
#pragma unroll
            for (int p = 0; p < 4; p++) {
                int m = bm + wm * 64 + i * 16 + qd * 4 + p;
                if (m < N_NODES) {
                    int n = bn + wn * 64 + j * 16 + ln;
                    C[(size_t)m * H1 + n] = f2bf(acc[i][j][p]);
                }
            }
    // fused a1s/a1d partial row-dots (this wave covers cols bn+wn*64 .. +63)
    float avs[4], avd[4];
#pragma unroll
    for (int j = 0; j < 4; j++) {
        int n = bn + wn * 64 + j * 16 + ln;
        avs[j] = atts[n];
        avd[j] = attd[n];
    }
#pragma unroll
    for (int i = 0; i < 4; i++)
#pragma unroll
        for (int p = 0; p < 4; p++) {
            float vs = 0.f, vd = 0.f;
#pragma unroll
            for (int j = 0; j < 4; j++) {
                vs += acc[i][j][p] * avs[j];
                vd += acc[i][j][p] * avd[j];
            }
#pragma unroll
            for (int msk = 1; msk < 16; msk <<= 1) {
                vs += __shfl_xor(vs, msk);
                vd += __shfl_xor(vd, msk);
            }
            if (ln == p) {
                int m = bm + wm * 64 + i * 16 + qd * 4 + p;
                if (m < N_NODES) {
                    unsafeAtomicAdd(a1s + m, vs);
                    unsafeAtomicAdd(a1d + m, vd);
                }
            }
        }
}

// ---- GEMM4 (MFMA, fused MSE): sum += (F - h3@W1^T)^2, XCD-swizzled ----------
__global__ __launch_bounds__(256) void gemm4_mse(const unsigned short* __restrict__ A,  // h3bf [20000,512]
                                                 const unsigned short* __restrict__ B,  // w1bf [2048,512]
                                                 const float* __restrict__ F,           // [20000,2048] fp32
                                                 float* __restrict__ partial) {
    __shared__ unsigned short As[128 * 40];
    __shared__ unsigned short Bs[128 * 40];
    __shared__ float red[256];
    const int blk = blockIdx.x;
    const int xcd = blk & 7, rr = blk >> 3;
    const int ntile = rr & 15, group = rr >> 4;
    const int stripe = group * 8 + xcd;
    if (stripe >= 157) return;
    const int bm = stripe * 128, bn = ntile * 128;
    const int t = threadIdx.x;
    const int lane = t & 63, w = t >> 6;
    const int wm = w >> 1, wn = w & 1;
    const int ln = lane & 15, qd = lane >> 4;
    const int r0 = t >> 2, cs = (t & 3) * 8;

    floatx4 acc[4][4];
#pragma unroll
    for (int i = 0; i < 4; i++)
#pragma unroll
        for (int j = 0; j < 4; j++) acc[i][j] = (floatx4){0.f, 0.f, 0.f, 0.f};

    for (int k0 = 0; k0 < H1; k0 += 32) {
#pragma unroll
        for (int part = 0; part < 2; part++) {
            int r = r0 + part * 64;
            int gr = bm + r; if (gr > N_NODES - 1) gr = N_NODES - 1;
            *(uint4*)&As[r * 40 + cs] = *(const uint4*)(A + (size_t)gr * H1 + k0 + cs);
            *(uint4*)&Bs[r * 40 + cs] = *(const uint4*)(B + (size_t)(bn + r) * H1 + k0 + cs);
        }
        __syncthreads();
        bf16x8 af[4], bfr[4];
        const unsigned short* Ab = As + (size_t)(wm * 64 + ln) * 40 + qd * 8;
        const unsigned short* Bb = Bs + (size_t)(wn * 64 + ln) * 40 + qd * 8;
#pragma unroll
        for (int i = 0; i < 4; i++) af[i]  = *(const bf16x8*)(const void*)(Ab + i * 16 * 40);
#pragma unroll
        for (int j = 0; j < 4; j++) bfr[j] = *(const bf16x8*)(const void*)(Bb + j * 16 * 40);
#pragma unroll
        for (int i = 0; i < 4; i++)
#pragma unroll
            for (int j = 0; j < 4; j++)
                acc[i][j] = __builtin_amdgcn_mfma_f32_16x16x32_bf16(af[i], bfr[j], acc[i][j], 0, 0, 0);
        __syncthreads();
    }
    float sum = 0.f;
#pragma unroll
    for (int i = 0; i < 4; i++)
#pragma unroll
        for (int j = 0; j < 4; j++)
#pragma unroll
            for (int p = 0; p < 4; p++) {
                int m = bm + wm * 64 + i * 16 + qd * 4 + p;
                if (m < N_NODES) {
                    int n = bn + wn * 64 + j * 16 + ln;
                    float fv = F[(size_t)m * N_FEAT + n];
                    float d = fv - acc[i][j][p];
                    sum += d * d;
                }
            }
    red[t] = sum;
    __syncthreads();
    for (int off = 128; off; off >>= 1) {
        if (t < off) red[t] += red[t + off];
        __syncthreads();
    }
    if (t == 0) unsafeAtomicAdd(partial, red[0]);
}

// ---- edge pass --------------------------------------------------------------
__global__ void edge_att(const int* __restrict__ ei,
                         const float* __restrict__ a1s,
                         const float* __restrict__ a1d,
                         float* __restrict__ ebuf,
                         float* __restrict__ den,
                         int* __restrict__ deg) {
    int e = blockIdx.x * blockDim.x + threadIdx.x;
    if (e >= E_TOT) return;
    int s, d;
    if (e < N_EDGESI) { s = ei[e]; d = ei[N_EDGESI + e]; }
    else { s = e - N_EDGESI; d = s; }
    float x = a1s[s] + a1d[d];
    float sig = 1.f / (1.f + __expf(-x));
    float ex = __expf(sig);
    ebuf[e] = ex;
    unsafeAtomicAdd(&den[d], ex);
    atomicAdd(&deg[d], 1);
}

// ---- exclusive prefix sum over deg -> off (wave-shuffle scan) ---------------
__global__ __launch_bounds__(1024) void scan_k(const int* __restrict__ deg,
                                               int* __restrict__ off) {
    __shared__ int wsum[16];
    __shared__ int carry_s;
    const int lane = threadIdx.x & 63, wid = threadIdx.x >> 6;
    if (threadIdx.x == 0) carry_s = 0;
    __syncthreads();
    for (int base = 0; base < N_NODES; base += 1024) {
        int i = base + threadIdx.x;
        int v = (i < N_NODES) ? deg[i] : 0;
        int x = v;
#pragma unroll
        for (int s = 1; s < 64; s <<= 1) {
            int tt = __shfl_up(x, s);
            if (lane >= s) x += tt;
        }
        if (lane == 63) wsum[wid] = x;
        __syncthreads();
        if (wid == 0 && lane < 16) {
            int wv = wsum[lane];
#pragma unroll
            for (int s = 1; s < 16; s <<= 1) {
                int tt = __shfl_up(wv, s);
                if (lane >= s) wv += tt;
            }
            wsum[lane] = wv;
        }
        __syncthreads();
        int wbase = (wid == 0) ? 0 : wsum[wid - 1];
        int c = carry_s;
        int incl = x + wbase + c;
        if (i < N_NODES) off[i] = incl - v;
        __syncthreads();
        if (threadIdx.x == 0) carry_s = c + wsum[15];
        __syncthreads();
    }
}

// ---- bucket edges into CSR slots -------------------------------------------
__global__ void bucket_k(const int* __restrict__ ei,
                         const float* __restrict__ ebuf,
                         const float* __restrict__ den,
                         int* __restrict__ cursor,
                         int* __restrict__ csr_src,
                         float* __restrict__ csr_coef) {
    int e = blockIdx.x * blockDim.x + threadIdx.x;
    if (e >= E_TOT) return;
    int s, d;
    if (e < N_EDGESI) { s = ei[e]; d = ei[N_EDGESI + e]; }
    else { s = e - N_EDGESI; d = s; }
    int pos = atomicAdd(&cursor[d], 1);
    csr_src[pos] = s;
    csr_coef[pos] = ebuf[e] / den[d];
}

// ---- gather (bf16): Y[d] = elu(sum coef * X[src]), unroll-2 dual acc --------
__global__ __launch_bounds__(256) void gather_elu_bf(const int* __restrict__ off,
                                                     const int* __restrict__ csr_src,
                                                     const float* __restrict__ csr_coef,
                                                     const unsigned short* __restrict__ X,
                                                     unsigned short* __restrict__ Y) {
    int d = blockIdx.x * 4 + (threadIdx.x >> 6);
    int lane = threadIdx.x & 63;
    if (d >= N_NODES) return;
    int beg = off[d];
    int end = (d == N_NODES - 1) ? E_TOT : off[d + 1];
    float a[8] = {0.f, 0.f, 0.f, 0.f, 0.f, 0.f, 0.f, 0.f};
    float b[8] = {0.f, 0.f, 0.f, 0.f, 0.f, 0.f, 0.f, 0.f};
    int j = beg;
    for (; j + 1 < end; j += 2) {
        int s0 = csr_src[j], s1 = csr_src[j + 1];
        float c0 = csr_coef[j], c1 = csr_coef[j + 1];
        uint4 raw0 = *(const uint4*)(X + (size_t)s0 * H1 + lane * 8);
        uint4 raw1 = *(const uint4*)(X + (size_t)s1 * H1 + lane * 8);
        a[0] += __uint_as_float(raw0.x << 16) * c0;
        a[1] += __uint_as_float(raw0.x & 0xFFFF0000u) * c0;
        a[2] += __uint_as_float(raw0.y << 16) * c0;
        a[3] += __uint_as_float(raw0.y & 0xFFFF0000u) * c0;
        a[4] += __uint_as_float(raw0.z << 16) * c0;
        a[5] += __uint_as_float(raw0.z & 0xFFFF0000u) * c0;
        a[6] += __uint_as_float(raw0.w << 16) * c0;
        a[7] += __uint_as_float(raw0.w & 0xFFFF0000u) * c0;
        b[0] += __uint_as_float(raw1.x << 16) * c1;
        b[1] += __uint_as_float(raw1.x & 0xFFFF0000u) * c1;
        b[2] += __uint_as_float(raw1.y << 16) * c1;
        b[3] += __uint_as_float(raw1.y & 0xFFFF0000u) * c1;
        b[4] += __uint_as_float(raw1.z << 16) * c1;
        b[5] += __uint_as_float(raw1.z & 0xFFFF0000u) * c1;
        b[6] += __uint_as_float(raw1.w << 16) * c1;
        b[7] += __uint_as_float(raw1.w & 0xFFFF0000u) * c1;
    }
    if (j < end) {
        int s0 = csr_src[j];
        float c0 = csr_coef[j];
        uint4 raw0 = *(const uint4*)(X + (size_t)s0 * H1 + lane * 8);
        a[0] += __uint_as_float(raw0.x << 16) * c0;
        a[1] += __uint_as_float(raw0.x & 0xFFFF0000u) * c0;
        a[2] += __uint_as_float(raw0.y << 16) * c0;
        a[3] += __uint_as_float(raw0.y & 0xFFFF0000u) * c0;
        a[4] += __uint_as_float(raw0.z << 16) * c0;
        a[5] += __uint_as_float(raw0.z & 0xFFFF0000u) * c0;
        a[6] += __uint_as_float(raw0.w << 16) * c0;
        a[7] += __uint_as_float(raw0.w & 0xFFFF0000u) * c0;
    }
#pragma unroll
    for (int e = 0; e < 8; e++) {
        float v = a[e] + b[e];
        a[e] = v > 0.f ? v : __expf(v) - 1.f;
    }
    uint4 o;
    o.x = packrne(a[0], a[1]);
    o.y = packrne(a[2], a[3]);
    o.z = packrne(a[4], a[5]);
    o.w = packrne(a[6], a[7]);
    *(uint4*)(Y + (size_t)d * H1 + lane * 8) = o;
}

// ---- h2 = normalize_rows(h1 @ W2), h1 in bf16 -------------------------------
__global__ __launch_bounds__(256) void gemm2_norm_bf(const unsigned short* __restrict__ H1b,
                                                     const float* __restrict__ W2,
                                                     float* __restrict__ h2n) {
    __shared__ float hs[8 * 516];
    const int n0 = blockIdx.x * 8;
    const int tid = threadIdx.x;
    for (int idx = tid; idx < 512; idx += 256) {
        int r = idx >> 6, c = (idx & 63) * 8;
        uint4 raw = *(const uint4*)(H1b + (size_t)(n0 + r) * H1 + c);
        float* hp = hs + r * 516 + c;
        hp[0] = __uint_as_float(raw.x << 16);
        hp[1] = __uint_as_float(raw.x & 0xFFFF0000u);
        hp[2] = __uint_as_float(raw.y << 16);
        hp[3] = __uint_as_float(raw.y & 0xFFFF0000u);
        hp[4] = __uint_as_float(raw.z << 16);
        hp[5] = __uint_as_float(raw.z & 0xFFFF0000u);
        hp[6] = __uint_as_float(raw.w << 16);
        hp[7] = __uint_as_float(raw.w & 0xFFFF0000u);
    }
    __syncthreads();
    const int sub = tid >> 5, j = tid & 31;
    float a0 = 0.f, a1 = 0.f, a2 = 0.f, a3 = 0.f;
    if (j < H2) {
        const float* hr = hs + sub * 516;
        for (int k = 0; k < H1; k += 4) {
            a0 += hr[k] * W2[k * H2 + j];
            a1 += hr[k + 1] * W2[(k + 1) * H2 + j];
            a2 += hr[k + 2] * W2[(k + 2) * H2 + j];
            a3 += hr[k + 3] * W2[(k + 3) * H2 + j];
        }
    }
    float acc = (a0 + a1) + (a2 + a3);
    float sq = acc * acc;
    for (int m = 16; m; m >>= 1) sq += __shfl_xor(sq, m, 32);
    float inv = 1.f / fmaxf(sqrtf(sq), 1e-12f);
    if (j < H2) h2n[(size_t)(n0 + sub) * H2 + j] = acc * inv;
}

// ---- xw3 = h2n @ W2^T -> bf16 ----------------------------------------------
__global__ void gemm3_k(const float* __restrict__ h2n,
                        const float* __restrict__ W2,
                        unsigned short* __restrict__ xw3) {
    int g = blockIdx.x * blockDim.x + threadIdx.x;  // 20000*512
    int n = g >> 9, h = g & 511;
    const float* hr = h2n + (size_t)n * H2;
    const float* wr = W2 + (size_t)h * H2;
    float acc = 0.f;
#pragma unroll
    for (int k = 0; k < H2; k++) acc += hr[k] * wr[k];
    xw3[g] = f2bf(acc);
}

__global__ void finalize_k(const float* __restrict__ partial, float* __restrict__ out) {
    out[0] = partial[0] * (1.f / ((float)N_NODES * (float)N_FEAT));
}

extern "C" void kernel_launch(void* const* d_in, const int* in_sizes, int n_in,
                              void* d_out, int out_size, void* d_ws, size_t ws_size,
                              hipStream_t stream) {
    const float* features = (const float*)d_in[0];
    const int*   ei       = (const int*)d_in[1];
    const float* W1       = (const float*)d_in[2];
    const float* atts     = (const float*)d_in[3];
    const float* attd     = (const float*)d_in[4];
    const float* W2       = (const float*)d_in[5];
    float* out = (float*)d_out;

    char* ws = (char*)d_ws;
    unsigned short* xw1bf = (unsigned short*)(ws);              // 20,480,000 B (also xw3bf)
    unsigned short* h3bf  = (unsigned short*)(ws + 20480000);   // 20,480,000 B
    unsigned short* h1bf  = (unsigned short*)(ws + 40960000);   // 20,480,000 B
    unsigned short* w1bf  = (unsigned short*)(ws + 61440000);   //  2,097,152 B
    unsigned short* w1tbf = (unsigned short*)(ws + 63537152);   //  2,097,152 B
    float* h2n      = (float*)(ws + 65634304);                  //  2,400,000 B
    // zero region (single memset): a1s,a1d,den,deg,partial
    float* a1s      = (float*)(ws + 68034304);                  // 80,000
    float* a1d      = (float*)(ws + 68114304);                  // 80,000
    float* den      = (float*)(ws + 68194304);                  // 80,000
    int*   deg      = (int*)  (ws + 68274304);                  // 80,000
    float* partial  = (float*)(ws + 68354304);                  // 16
    float* ebuf     = (float*)(ws + 68354320);                  // 880,000
    int*   off      = (int*)  (ws + 69234320);
    int*   cursor   = (int*)  (ws + 69314320);
    int*   csr_src  = (int*)  (ws + 69394320);                  // 880,000
    float* csr_coef = (float*)(ws + 70274320);                  // 880,000

    hipMemsetAsync(a1s, 0, 320016, stream);  // a1s,a1d,den,deg,partial

    // 0) W1 -> bf16 (straight + transposed)
    cvtW1<<<dim3(16, 64), 256, 0, stream>>>(W1, w1bf, w1tbf);

    // 1) xw1 = features @ W1 (MFMA) with fused a1s/a1d epilogue, XCD-swizzled
    gemm1_mfma<<<640, 256, 0, stream>>>(features, w1tbf, xw1bf, atts, attd, a1s, a1d);

    // 2) edge attention numerators + denominators + degree counts
    edge_att<<<(E_TOT + 255) / 256, 256, 0, stream>>>(ei, a1s, a1d, ebuf, den, deg);

    // 3) CSR build
    scan_k<<<1, 1024, 0, stream>>>(deg, off);
    hipMemcpyAsync(cursor, off, 20000 * 4, hipMemcpyDeviceToDevice, stream);
    bucket_k<<<(E_TOT + 255) / 256, 256, 0, stream>>>(ei, ebuf, den, cursor, csr_src, csr_coef);

    // 4) h1 = elu(gather(xw1))
    gather_elu_bf<<<N_NODES / 4, 256, 0, stream>>>(off, csr_src, csr_coef, xw1bf, h1bf);

    // 5) h2n = normalize_rows(h1 @ W2)
    gemm2_norm_bf<<<N_NODES / 8, 256, 0, stream>>>(h1bf, W2, h2n);

    // 6) xw3 = h2n @ W2^T (bf16 out, reuses xw1bf buffer)
    gemm3_k<<<10240000 / 256, 256, 0, stream>>>(h2n, W2, xw1bf);

    // 7) h3 = elu(gather(xw3))
    gather_elu_bf<<<N_NODES / 4, 256, 0, stream>>>(off, csr_src, csr_coef, xw1bf, h3bf);

    // 8) fused h4 = h3 @ W1^T with MSE reduction (MFMA), XCD-swizzled
    gemm4_mse<<<2560, 256, 0, stream>>>(h3bf, w1bf, features, partial);

    // 9) finalize
    finalize_k<<<1, 1, 0, stream>>>(partial, out);
}

// Round 5
// 751.589 us; speedup vs baseline: 6.5223x; 1.0205x over previous
//
#include <hip/hip_runtime.h>
#include <math.h>

#define N_NODES 20000
#define N_EDGESI 200000
#define E_TOT   220000
#define N_FEAT  2048
#define H1      512
#define H2      30

typedef __bf16 bf16x8 __attribute__((ext_vector_type(8)));
typedef float  floatx4 __attribute__((ext_vector_type(4)));

__device__ __forceinline__ unsigned short f2bf(float f) {   // RNE
    unsigned int u = __float_as_uint(f);
    unsigned int r = (u + 0x7FFF + ((u >> 16) & 1)) >> 16;
    return (unsigned short)r;
}
__device__ __forceinline__ float bf2f(unsigned short u) {
    return __uint_as_float(((unsigned int)u) << 16);
}
__device__ __forceinline__ unsigned int packtrunc(float a, float b) {
    return (__float_as_uint(a) >> 16) | (__float_as_uint(b) & 0xFFFF0000u);
}
__device__ __forceinline__ unsigned int packrne(float a, float b) {
    return (unsigned int)f2bf(a) | ((unsigned int)f2bf(b) << 16);
}

// ---- W1 conversion: w1bf[k][n] (straight) + w1tbf[n][k] (transposed) -------
__global__ __launch_bounds__(256) void cvtW1(const float* __restrict__ W1,
                                             unsigned short* __restrict__ w1bf,
                                             unsigned short* __restrict__ w1tbf) {
    __shared__ float tile[32][33];
    const int bk = blockIdx.y * 32, bn = blockIdx.x * 32;
    const int tc = threadIdx.x & 31, tr = threadIdx.x >> 5;  // 8 rows/pass
    for (int r = tr; r < 32; r += 8) {
        float v = W1[(size_t)(bk + r) * H1 + bn + tc];
        w1bf[(size_t)(bk + r) * H1 + bn + tc] = f2bf(v);
        tile[r][tc] = v;
    }
    __syncthreads();
    for (int r = tr; r < 32; r += 8) {
        w1tbf[(size_t)(bn + r) * N_FEAT + bk + tc] = f2bf(tile[tc][r]);
    }
}

// ---- GEMM1 (MFMA, reg-prefetch pipeline): xw1 = features @ W1 ---------------
// fused a1s/a1d epilogue; XCD-swizzled grid (4 N-tiles of a stripe share L2).
__global__ __launch_bounds__(256) void gemm1_mfma(const float* __restrict__ A,          // [20000,2048] fp32
                                                  const unsigned short* __restrict__ Bt, // [512,2048] bf16
                                                  unsigned short* __restrict__ C,        // [20000,512] bf16
                                                  const float* __restrict__ atts,
                                                  const float* __restrict__ attd,
                                                  float* __restrict__ a1s,
                                                  float* __restrict__ a1d) {
    __shared__ unsigned short As[128 * 40];
    __shared__ unsigned short Bs[128 * 40];
    const int blk = blockIdx.x;
    const int xcd = blk & 7, rr = blk >> 3;
    const int ntile = rr & 3, group = rr >> 2;
    const int stripe = group * 8 + xcd;
    if (stripe >= 157) return;
    const int bm = stripe * 128, bn = ntile * 128;
    const int t = threadIdx.x;
    const int lane = t & 63, w = t >> 6;
    const int wm = w >> 1, wn = w & 1;
    const int ln = lane & 15, qd = lane >> 4;
    const int r0 = t >> 2, cs = (t & 3) * 8;

    // global base pointers for this thread's staging slice
    int gr0 = bm + r0;        if (gr0 > N_NODES - 1) gr0 = N_NODES - 1;
    int gr1 = bm + r0 + 64;   if (gr1 > N_NODES - 1) gr1 = N_NODES - 1;
    const float* ap0 = A + (size_t)gr0 * N_FEAT + cs;
    const float* ap1 = A + (size_t)gr1 * N_FEAT + cs;
    const unsigned short* bp0 = Bt + (size_t)(bn + r0) * N_FEAT + cs;
    const unsigned short* bp1 = Bt + (size_t)(bn + r0 + 64) * N_FEAT + cs;

    floatx4 acc[4][4];
#pragma unroll
    for (int i = 0; i < 4; i++)
#pragma unroll
        for (int j = 0; j < 4; j++) acc[i][j] = (floatx4){0.f, 0.f, 0.f, 0.f};

    // prologue: load tile 0 into registers
    float4 pa00 = *(const float4*)(ap0);
    float4 pa01 = *(const float4*)(ap0 + 4);
    float4 pa10 = *(const float4*)(ap1);
    float4 pa11 = *(const float4*)(ap1 + 4);
    uint4  pb0  = *(const uint4*)(bp0);
    uint4  pb1  = *(const uint4*)(bp1);

    for (int k0 = 0; k0 < N_FEAT; k0 += 32) {
        // stage current regs -> LDS
        uint4 pk0, pk1;
        pk0.x = packtrunc(pa00.x, pa00.y); pk0.y = packtrunc(pa00.z, pa00.w);
        pk0.z = packtrunc(pa01.x, pa01.y); pk0.w = packtrunc(pa01.z, pa01.w);
        pk1.x = packtrunc(pa10.x, pa10.y); pk1.y = packtrunc(pa10.z, pa10.w);
        pk1.z = packtrunc(pa11.x, pa11.y); pk1.w = packtrunc(pa11.z, pa11.w);
        *(uint4*)&As[r0 * 40 + cs] = pk0;
        *(uint4*)&As[(r0 + 64) * 40 + cs] = pk1;
        *(uint4*)&Bs[r0 * 40 + cs] = pb0;
        *(uint4*)&Bs[(r0 + 64) * 40 + cs] = pb1;
        __syncthreads();
        // prefetch next tile (overlaps MFMA + ds_read below)
        const bool more = (k0 + 32) < N_FEAT;
        if (more) {
            int kn = k0 + 32;
            pa00 = *(const float4*)(ap0 + kn);
            pa01 = *(const float4*)(ap0 + kn + 4);
            pa10 = *(const float4*)(ap1 + kn);
            pa11 = *(const float4*)(ap1 + kn + 4);
            pb0  = *(const uint4*)(bp0 + kn);
            pb1  = *(const uint4*)(bp1 + kn);
        }
        // compute from LDS
        bf16x8 af[4], bfr[4];
        const unsigned short* Ab = As + (size_t)(wm * 64 + ln) * 40 + qd * 8;
        const unsigned short* Bb = Bs + (size_t)(wn * 64 + ln) * 40 + qd * 8;
#pragma unroll
        for (int i = 0; i < 4; i++) af[i]  = *(const bf16x8*)(const void*)(Ab + i * 16 * 40);
#pragma unroll
        for (int j = 0; j < 4; j++) bfr[j] = *(const bf16x8*)(const void*)(Bb + j * 16 * 40);
#pragma unroll
        for (int i = 0; i < 4; i++)
#pragma unroll
            for (int j = 0; j < 4; j++)
                acc[i][j] = __builtin_amdgcn_mfma_f32_16x16x32_bf16(af[i], bfr[j], acc[i][j], 0, 0, 0);
        __syncthreads();
    }
    // C write
#pragma unroll
    for (int i = 0; i < 4; i++)
#pragma unroll
        for (int j = 0; j < 4; j++)
#pragma unroll
            for (int p = 0; p < 4; p++) {
                int m = bm + wm * 64 + i * 16 + qd * 4 + p;
                if (m < N_NODES) {
                    int n = bn + wn * 64 + j * 16 + ln;
                    C[(size_t)m * H1 + n] = f2bf(acc[i][j][p]);
                }
            }
    // fused a1s/a1d partial row-dots (this wave covers cols bn+wn*64 .. +63)
    float avs[4], avd[4];
#pragma unroll
    for (int j = 0; j < 4; j++) {
        int n = bn + wn * 64 + j * 16 + ln;
        avs[j] = atts[n];
        avd[j] = attd[n];
    }
#pragma unroll
    for (int i = 0; i < 4; i++)
#pragma unroll
        for (int p = 0; p < 4; p++) {
            float vs = 0.f, vd = 0.f;
#pragma unroll
            for (int j = 0; j < 4; j++) {
                vs += acc[i][j][p] * avs[j];
                vd += acc[i][j][p] * avd[j];
            }
#pragma unroll
            for (int msk = 1; msk < 16; msk <<= 1) {
                vs += __shfl_xor(vs, msk);
                vd += __shfl_xor(vd, msk);
            }
            if (ln == p) {
                int m = bm + wm * 64 + i * 16 + qd * 4 + p;
                if (m < N_NODES) {
                    unsafeAtomicAdd(a1s + m, vs);
                    unsafeAtomicAdd(a1d + m, vd);
                }
            }
        }
}

// ---- GEMM4 (MFMA, reg-prefetch, fused MSE): sum += (F - h3@W1^T)^2 ----------
__global__ __launch_bounds__(256) void gemm4_mse(const unsigned short* __restrict__ A,  // h3bf [20000,512]
                                                 const unsigned short* __restrict__ B,  // w1bf [2048,512]
                                                 const float* __restrict__ F,           // [20000,2048] fp32
                                                 float* __restrict__ partial) {
    __shared__ unsigned short As[128 * 40];
    __shared__ unsigned short Bs[128 * 40];
    __shared__ float red[256];
    const int blk = blockIdx.x;
    const int xcd = blk & 7, rr = blk >> 3;
    const int ntile = rr & 15, group = rr >> 4;
    const int stripe = group * 8 + xcd;
    if (stripe >= 157) return;
    const int bm = stripe * 128, bn = ntile * 128;
    const int t = threadIdx.x;
    const int lane = t & 63, w = t >> 6;
    const int wm = w >> 1, wn = w & 1;
    const int ln = lane & 15, qd = lane >> 4;
    const int r0 = t >> 2, cs = (t & 3) * 8;

    int gr0 = bm + r0;        if (gr0 > N_NODES - 1) gr0 = N_NODES - 1;
    int gr1 = bm + r0 + 64;   if (gr1 > N_NODES - 1) gr1 = N_NODES - 1;
    const unsigned short* ap0 = A + (size_t)gr0 * H1 + cs;
    const unsigned short* ap1 = A + (size_t)gr1 * H1 + cs;
    const unsigned short* bp0 = B + (size_t)(bn + r0) * H1 + cs;
    const unsigned short* bp1 = B + (size_t)(bn + r0 + 64) * H1 + cs;

    floatx4 acc[4][4];
#pragma unroll
    for (int i = 0; i < 4; i++)
#pragma unroll
        for (int j = 0; j < 4; j++) acc[i][j] = (floatx4){0.f, 0.f, 0.f, 0.f};

    uint4 pa0 = *(const uint4*)(ap0);
    uint4 pa1 = *(const uint4*)(ap1);
    uint4 pb0 = *(const uint4*)(bp0);
    uint4 pb1 = *(const uint4*)(bp1);

    for (int k0 = 0; k0 < H1; k0 += 32) {
        *(uint4*)&As[r0 * 40 + cs] = pa0;
        *(uint4*)&As[(r0 + 64) * 40 + cs] = pa1;
        *(uint4*)&Bs[r0 * 40 + cs] = pb0;
        *(uint4*)&Bs[(r0 + 64) * 40 + cs] = pb1;
        __syncthreads();
        const bool more = (k0 + 32) < H1;
        if (more) {
            int kn = k0 + 32;
            pa0 = *(const uint4*)(ap0 + kn);
            pa1 = *(const uint4*)(ap1 + kn);
            pb0 = *(const uint4*)(bp0 + kn);
            pb1 = *(const uint4*)(bp1 + kn);
        }
        bf16x8 af[4], bfr[4];
        const unsigned short* Ab = As + (size_t)(wm * 64 + ln) * 40 + qd * 8;
        const unsigned short* Bb = Bs + (size_t)(wn * 64 + ln) * 40 + qd * 8;
#pragma unroll
        for (int i = 0; i < 4; i++) af[i]  = *(const bf16x8*)(const void*)(Ab + i * 16 * 40);
#pragma unroll
        for (int j = 0; j < 4; j++) bfr[j] = *(const bf16x8*)(const void*)(Bb + j * 16 * 40);
#pragma unroll
        for (int i = 0; i < 4; i++)
#pragma unroll
            for (int j = 0; j < 4; j++)
                acc[i][j] = __builtin_amdgcn_mfma_f32_16x16x32_bf16(af[i], bfr[j], acc[i][j], 0, 0, 0);
        __syncthreads();
    }
    float sum = 0.f;
#pragma unroll
    for (int i = 0; i < 4; i++)
#pragma unroll
        for (int j = 0; j < 4; j++)
#pragma unroll
            for (int p = 0; p < 4; p++) {
                int m = bm + wm * 64 + i * 16 + qd * 4 + p;
                if (m < N_NODES) {
                    int n = bn + wn * 64 + j * 16 + ln;
                    float fv = F[(size_t)m * N_FEAT + n];
                    float d = fv - acc[i][j][p];
                    sum += d * d;
                }
            }
    red[t] = sum;
    __syncthreads();
    for (int off = 128; off; off >>= 1) {
        if (t < off) red[t] += red[t + off];
        __syncthreads();
    }
    if (t == 0) unsafeAtomicAdd(partial, red[0]);
}

// ---- edge pass --------------------------------------------------------------
__global__ void edge_att(const int* __restrict__ ei,
                         const float* __restrict__ a1s,
                         const float* __restrict__ a1d,
                         float* __restrict__ ebuf,
                         float* __restrict__ den,
                         int* __restrict__ deg) {
    int e = blockIdx.x * blockDim.x + threadIdx.x;
    if (e >= E_TOT) return;
    int s, d;
    if (e < N_EDGESI) { s = ei[e]; d = ei[N_EDGESI + e]; }
    else { s = e - N_EDGESI; d = s; }
    float x = a1s[s] + a1d[d];
    float sig = 1.f / (1.f + __expf(-x));
    float ex = __expf(sig);
    ebuf[e] = ex;
    unsafeAtomicAdd(&den[d], ex);
    atomicAdd(&deg[d], 1);
}

// ---- exclusive prefix sum over deg -> off (wave-shuffle scan) ---------------
__global__ __launch_bounds__(1024) void scan_k(const int* __restrict__ deg,
                                               int* __restrict__ off) {
    __shared__ int wsum[16];
    __shared__ int carry_s;
    const int lane = threadIdx.x & 63, wid = threadIdx.x >> 6;
    if (threadIdx.x == 0) carry_s = 0;
    __syncthreads();
    for (int base = 0; base < N_NODES; base += 1024) {
        int i = base + threadIdx.x;
        int v = (i < N_NODES) ? deg[i] : 0;
        int x = v;
#pragma unroll
        for (int s = 1; s < 64; s <<= 1) {
            int tt = __shfl_up(x, s);
            if (lane >= s) x += tt;
        }
        if (lane == 63) wsum[wid] = x;
        __syncthreads();
        if (wid == 0 && lane < 16) {
            int wv = wsum[lane];
#pragma unroll
            for (int s = 1; s < 16; s <<= 1) {
                int tt = __shfl_up(wv, s);
                if (lane >= s) wv += tt;
            }
            wsum[lane] = wv;
        }
        __syncthreads();
        int wbase = (wid == 0) ? 0 : wsum[wid - 1];
        int c = carry_s;
        int incl = x + wbase + c;
        if (i < N_NODES) off[i] = incl - v;
        __syncthreads();
        if (threadIdx.x == 0) carry_s = c + wsum[15];
        __syncthreads();
    }
}

// ---- bucket edges into CSR slots -------------------------------------------
__global__ void bucket_k(const int* __restrict__ ei,
                         const float* __restrict__ ebuf,
                         const float* __restrict__ den,
                         int* __restrict__ cursor,
                         int* __restrict__ csr_src,
                         float* __restrict__ csr_coef) {
    int e = blockIdx.x * blockDim.x + threadIdx.x;
    if (e >= E_TOT) return;
    int s, d;
    if (e < N_EDGESI) { s = ei[e]; d = ei[N_EDGESI + e]; }
    else { s = e - N_EDGESI; d = s; }
    int pos = atomicAdd(&cursor[d], 1);
    csr_src[pos] = s;
    csr_coef[pos] = ebuf[e] / den[d];
}

// ---- gather (bf16): Y[d] = elu(sum coef * X[src]), unroll-2 dual acc --------
__global__ __launch_bounds__(256) void gather_elu_bf(const int* __restrict__ off,
                                                     const int* __restrict__ csr_src,
                                                     const float* __restrict__ csr_coef,
                                                     const unsigned short* __restrict__ X,
                                                     unsigned short* __restrict__ Y) {
    int d = blockIdx.x * 4 + (threadIdx.x >> 6);
    int lane = threadIdx.x & 63;
    if (d >= N_NODES) return;
    int beg = off[d];
    int end = (d == N_NODES - 1) ? E_TOT : off[d + 1];
    float a[8] = {0.f, 0.f, 0.f, 0.f, 0.f, 0.f, 0.f, 0.f};
    float b[8] = {0.f, 0.f, 0.f, 0.f, 0.f, 0.f, 0.f, 0.f};
    int j = beg;
    for (; j + 1 < end; j += 2) {
        int s0 = csr_src[j], s1 = csr_src[j + 1];
        float c0 = csr_coef[j], c1 = csr_coef[j + 1];
        uint4 raw0 = *(const uint4*)(X + (size_t)s0 * H1 + lane * 8);
        uint4 raw1 = *(const uint4*)(X + (size_t)s1 * H1 + lane * 8);
        a[0] += __uint_as_float(raw0.x << 16) * c0;
        a[1] += __uint_as_float(raw0.x & 0xFFFF0000u) * c0;
        a[2] += __uint_as_float(raw0.y << 16) * c0;
        a[3] += __uint_as_float(raw0.y & 0xFFFF0000u) * c0;
        a[4] += __uint_as_float(raw0.z << 16) * c0;
        a[5] += __uint_as_float(raw0.z & 0xFFFF0000u) * c0;
        a[6] += __uint_as_float(raw0.w << 16) * c0;
        a[7] += __uint_as_float(raw0.w & 0xFFFF0000u) * c0;
        b[0] += __uint_as_float(raw1.x << 16) * c1;
        b[1] += __uint_as_float(raw1.x & 0xFFFF0000u) * c1;
        b[2] += __uint_as_float(raw1.y << 16) * c1;
        b[3] += __uint_as_float(raw1.y & 0xFFFF0000u) * c1;
        b[4] += __uint_as_float(raw1.z << 16) * c1;
        b[5] += __uint_as_float(raw1.z & 0xFFFF0000u) * c1;
        b[6] += __uint_as_float(raw1.w << 16) * c1;
        b[7] += __uint_as_float(raw1.w & 0xFFFF0000u) * c1;
    }
    if (j < end) {
        int s0 = csr_src[j];
        float c0 = csr_coef[j];
        uint4 raw0 = *(const uint4*)(X + (size_t)s0 * H1 + lane * 8);
        a[0] += __uint_as_float(raw0.x << 16) * c0;
        a[1] += __uint_as_float(raw0.x & 0xFFFF0000u) * c0;
        a[2] += __uint_as_float(raw0.y << 16) * c0;
        a[3] += __uint_as_float(raw0.y & 0xFFFF0000u) * c0;
        a[4] += __uint_as_float(raw0.z << 16) * c0;
        a[5] += __uint_as_float(raw0.z & 0xFFFF0000u) * c0;
        a[6] += __uint_as_float(raw0.w << 16) * c0;
        a[7] += __uint_as_float(raw0.w & 0xFFFF0000u) * c0;
    }
#pragma unroll
    for (int e = 0; e < 8; e++) {
        float v = a[e] + b[e];
        a[e] = v > 0.f ? v : __expf(v) - 1.f;
    }
    uint4 o;
    o.x = packrne(a[0], a[1]);
    o.y = packrne(a[2], a[3]);
    o.z = packrne(a[4], a[5]);
    o.w = packrne(a[6], a[7]);
    *(uint4*)(Y + (size_t)d * H1 + lane * 8) = o;
}

// ---- h2 = normalize_rows(h1 @ W2), h1 in bf16 -------------------------------
__global__ __launch_bounds__(256) void gemm2_norm_bf(const unsigned short* __restrict__ H1b,
                                                     const float* __restrict__ W2,
                                                     float* __restrict__ h2n) {
    __shared__ float hs[8 * 516];
    const int n0 = blockIdx.x * 8;
    const int tid = threadIdx.x;
    for (int idx = tid; idx < 512; idx += 256) {
        int r = idx >> 6, c = (idx & 63) * 8;
        uint4 raw = *(const uint4*)(H1b + (size_t)(n0 + r) * H1 + c);
        float* hp = hs + r * 516 + c;
        hp[0] = __uint_as_float(raw.x << 16);
        hp[1] = __uint_as_float(raw.x & 0xFFFF0000u);
        hp[2] = __uint_as_float(raw.y << 16);
        hp[3] = __uint_as_float(raw.y & 0xFFFF0000u);
        hp[4] = __uint_as_float(raw.z << 16);
        hp[5] = __uint_as_float(raw.z & 0xFFFF0000u);
        hp[6] = __uint_as_float(raw.w << 16);
        hp[7] = __uint_as_float(raw.w & 0xFFFF0000u);
    }
    __syncthreads();
    const int sub = tid >> 5, j = tid & 31;
    float a0 = 0.f, a1 = 0.f, a2 = 0.f, a3 = 0.f;
    if (j < H2) {
        const float* hr = hs + sub * 516;
        for (int k = 0; k < H1; k += 4) {
            a0 += hr[k] * W2[k * H2 + j];
            a1 += hr[k + 1] * W2[(k + 1) * H2 + j];
            a2 += hr[k + 2] * W2[(k + 2) * H2 + j];
            a3 += hr[k + 3] * W2[(k + 3) * H2 + j];
        }
    }
    float acc = (a0 + a1) + (a2 + a3);
    float sq = acc * acc;
    for (int m = 16; m; m >>= 1) sq += __shfl_xor(sq, m, 32);
    float inv = 1.f / fmaxf(sqrtf(sq), 1e-12f);
    if (j < H2) h2n[(size_t)(n0 + sub) * H2 + j] = acc * inv;
}

// ---- xw3 = h2n @ W2^T -> bf16 ----------------------------------------------
__global__ void gemm3_k(const float* __restrict__ h2n,
                        const float* __restrict__ W2,
                        unsigned short* __restrict__ xw3) {
    int g = blockIdx.x * blockDim.x + threadIdx.x;  // 20000*512
    int n = g >> 9, h = g & 511;
    const float* hr = h2n + (size_t)n * H2;
    const float* wr = W2 + (size_t)h * H2;
    float acc = 0.f;
#pragma unroll
    for (int k = 0; k < H2; k++) acc += hr[k] * wr[k];
    xw3[g] = f2bf(acc);
}

__global__ void finalize_k(const float* __restrict__ partial, float* __restrict__ out) {
    out[0] = partial[0] * (1.f / ((float)N_NODES * (float)N_FEAT));
}

extern "C" void kernel_launch(void* const* d_in, const int* in_sizes, int n_in,
                              void* d_out, int out_size, void* d_ws, size_t ws_size,
                              hipStream_t stream) {
    const float* features = (const float*)d_in[0];
    const int*   ei       = (const int*)d_in[1];
    const float* W1       = (const float*)d_in[2];
    const float* atts     = (const float*)d_in[3];
    const float* attd     = (const float*)d_in[4];
    const float* W2       = (const float*)d_in[5];
    float* out = (float*)d_out;

    char* ws = (char*)d_ws;
    unsigned short* xw1bf = (unsigned short*)(ws);              // 20,480,000 B (also xw3bf)
    unsigned short* h3bf  = (unsigned short*)(ws + 20480000);   // 20,480,000 B
    unsigned short* h1bf  = (unsigned short*)(ws + 40960000);   // 20,480,000 B
    unsigned short* w1bf  = (unsigned short*)(ws + 61440000);   //  2,097,152 B
    unsigned short* w1tbf = (unsigned short*)(ws + 63537152);   //  2,097,152 B
    float* h2n      = (float*)(ws + 65634304);                  //  2,400,000 B
    // zero region (single memset): a1s,a1d,den,deg,partial
    float* a1s      = (float*)(ws + 68034304);                  // 80,000
    float* a1d      = (float*)(ws + 68114304);                  // 80,000
    float* den      = (float*)(ws + 68194304);                  // 80,000
    int*   deg      = (int*)  (ws + 68274304);                  // 80,000
    float* partial  = (float*)(ws + 68354304);                  // 16
    float* ebuf     = (float*)(ws + 68354320);                  // 880,000
    int*   off      = (int*)  (ws + 69234320);
    int*   cursor   = (int*)  (ws + 69314320);
    int*   csr_src  = (int*)  (ws + 69394320);                  // 880,000
    float* csr_coef = (float*)(ws + 70274320);                  // 880,000

    hipMemsetAsync(a1s, 0, 320016, stream);  // a1s,a1d,den,deg,partial

    // 0) W1 -> bf16 (straight + transposed)
    cvtW1<<<dim3(16, 64), 256, 0, stream>>>(W1, w1bf, w1tbf);

    // 1) xw1 = features @ W1 (MFMA, pipelined) + fused a1s/a1d, XCD-swizzled
    gemm1_mfma<<<640, 256, 0, stream>>>(features, w1tbf, xw1bf, atts, attd, a1s, a1d);

    // 2) edge attention numerators + denominators + degree counts
    edge_att<<<(E_TOT + 255) / 256, 256, 0, stream>>>(ei, a1s, a1d, ebuf, den, deg);

    // 3) CSR build
    scan_k<<<1, 1024, 0, stream>>>(deg, off);
    hipMemcpyAsync(cursor, off, 20000 * 4, hipMemcpyDeviceToDevice, stream);
    bucket_k<<<(E_TOT + 255) / 256, 256, 0, stream>>>(ei, ebuf, den, cursor, csr_src, csr_coef);

    // 4) h1 = elu(gather(xw1))
    gather_elu_bf<<<N_NODES / 4, 256, 0, stream>>>(off, csr_src, csr_coef, xw1bf, h1bf);

    // 5) h2n = normalize_rows(h1 @ W2)
    gemm2_norm_bf<<<N_NODES / 8, 256, 0, stream>>>(h1bf, W2, h2n);

    // 6) xw3 = h2n @ W2^T (bf16 out, reuses xw1bf buffer)
    gemm3_k<<<10240000 / 256, 256, 0, stream>>>(h2n, W2, xw1bf);

    // 7) h3 = elu(gather(xw3))
    gather_elu_bf<<<N_NODES / 4, 256, 0, stream>>>(off, csr_src, csr_coef, xw1bf, h3bf);

    // 8) fused h4 = h3 @ W1^T with MSE reduction (MFMA, pipelined), XCD-swizzled
    gemm4_mse<<<2560, 256, 0, stream>>>(h3bf, w1bf, features, partial);

    // 9) finalize
    finalize_k<<<1, 1, 0, stream>>>(partial, out);
}